// Round 5
// baseline (143.813 us; speedup 1.0000x reference)
//
#include <hip/hip_runtime.h>
#include <math.h>

// Problem constants
#define NB 8      // batch
#define NC 256    // channels
#define NN 1024   // spatial H*W
#define NICH 64   // inter channels

// ws layout (float offsets)
#define WS_AQ    0        // [256]
#define WS_AK    256      // [256]
#define WS_CQ    512
#define WS_CK    513
#define WS_GE    514
#define WS_MOM   520      // [32][4]: Seq,Sek,Sek2,Sekq partials per (b,qchunk)
#define WS_SX    1024     // [8][256]
#define WS_XE    3072     // [8][256]
#define WS_XK    5120     // [8][256]
#define WS_SX2P  7168     // [128]
#define WS_UUP   7296     // [128]
#define WS_T1P   7424     // [64]
#define WS_T2P   7488     // [64]
#define WS_VSU   7680     // [8][256]  u·1
#define WS_UE    9728     // [8][256]  u·eq
#define WS_VEU   11776    // [8][256]  u·ek
#define WS_CAQ   13824    // [8][256]  x·(u^T aq)
#define WS_CAK   15872    // [8][256]  x·(u^T ak)
#define WS_CUAK  17920    // [8][256]  u·(u^T ak)
#define WS_STAT  20480    // [8] stride 2560: eq,ek,Sv,Sve
#define STAT_STRIDE 2560
#define ST_EQ    0        // [1024]
#define ST_EK    1024     // [1024]
#define ST_SV    2048     // [256]
#define ST_SVE   2304     // [256]
#define WS_MAQ   40960    // [8][1024]  u^T aq
#define WS_MAK   49152    // [8][1024]  u^T ak
#define WS_EQP   57344    // [128][1024]
#define WS_EKP   188416   // [128][1024]
#define WS_MAQP  319488   // [128][1024]
#define WS_MAKP  450560   // [128][1024] ends 581632 floats

// k1: per (b,16-ch group): eq/ek partials and maq/mak partials over n, sx per channel.
__global__ void k1(const float* __restrict__ x, const float* __restrict__ u,
                   const float* __restrict__ Wq, const float* __restrict__ bq,
                   const float* __restrict__ Wk, const float* __restrict__ bk,
                   const float* __restrict__ Wc, float* __restrict__ ws) {
    const int bid = blockIdx.x;          // 128: b*16+g
    const int b = bid >> 4, g = bid & 15;
    const int t = threadIdx.x;           // 256
    const int c0 = g * 16;
    __shared__ float aql[16], akl[16];
    __shared__ float sxw[16][4];
    if (t < 16) {
        float a = 0.f, k = 0.f;
        for (int o = 0; o < NICH; ++o) {
            a += Wc[o] * Wq[o * NC + c0 + t];
            k += Wc[NICH + o] * Wk[o * NC + c0 + t];
        }
        aql[t] = a; akl[t] = k;
        ws[WS_AQ + c0 + t] = a;
        ws[WS_AK + c0 + t] = k;
    }
    if (t == 16) { float s = 0.f; for (int o = 0; o < 64; ++o) s += Wc[o] * bq[o]; ws[WS_CQ] = s; }
    if (t == 17) { float s = 0.f; for (int o = 0; o < 64; ++o) s += Wc[NICH + o] * bk[o]; ws[WS_CK] = s; }
    __syncthreads();
    const float* xb = x + ((size_t)b * NC + c0) * NN;
    const float* ub = u + ((size_t)b * NC + c0) * NN;
    float eqp[4] = {0.f, 0.f, 0.f, 0.f}, ekp[4] = {0.f, 0.f, 0.f, 0.f};
    float map[4] = {0.f, 0.f, 0.f, 0.f}, mkp[4] = {0.f, 0.f, 0.f, 0.f};
    const int wid = t >> 6, lane = t & 63;
    for (int c = 0; c < 16; ++c) {
        float a = aql[c], k = akl[c];
        float xs = 0.f;
#pragma unroll
        for (int jj = 0; jj < 4; ++jj) {
            float xv = xb[c * NN + t + 256 * jj];
            float uv = ub[c * NN + t + 256 * jj];
            eqp[jj] += a * xv; ekp[jj] += k * xv;
            map[jj] += a * uv; mkp[jj] += k * uv;
            xs += xv;
        }
        for (int off = 32; off > 0; off >>= 1) xs += __shfl_down(xs, off, 64);
        if (lane == 0) sxw[c][wid] = xs;
    }
    __syncthreads();
    if (t < 16) ws[WS_SX + b * NC + c0 + t] = sxw[t][0] + sxw[t][1] + sxw[t][2] + sxw[t][3];
    size_t pb = (size_t)bid * 1024;
#pragma unroll
    for (int jj = 0; jj < 4; ++jj) {
        ws[WS_EQP  + pb + t + 256 * jj] = eqp[jj];
        ws[WS_EKP  + pb + t + 256 * jj] = ekp[jj];
        ws[WS_MAQP + pb + t + 256 * jj] = map[jj];
        ws[WS_MAKP + pb + t + 256 * jj] = mkp[jj];
    }
}

// k2: finalize eq/ek + maq/mak, 4 moments (Seq, Sek, Sek2, Sekq)
__global__ void k2(float* __restrict__ ws) {
    const int bid = blockIdx.x;      // 32: b*4+qc
    const int b = bid >> 2, qc = bid & 3;
    const int t = threadIdx.x;       // 256
    const int n = qc * 256 + t;
    const float cq = ws[WS_CQ], ck = ws[WS_CK];
    float e = 0.f, k = 0.f, ma = 0.f, mk = 0.f;
    for (int g = 0; g < 16; ++g) {
        size_t pb = (size_t)(b * 16 + g) * 1024 + n;
        e  += ws[WS_EQP  + pb];
        k  += ws[WS_EKP  + pb];
        ma += ws[WS_MAQP + pb];
        mk += ws[WS_MAKP + pb];
    }
    e += cq; k += ck;
    float* st = ws + WS_STAT + b * STAT_STRIDE;
    st[ST_EQ + n] = e;
    st[ST_EK + n] = k;
    ws[WS_MAQ + b * NN + n] = ma;
    ws[WS_MAK + b * NN + n] = mk;
    float d[4] = {e, k, k * k, e * k};
    __shared__ float dred[4][4];
    const int wid = t >> 6, lane = t & 63;
    for (int off = 32; off > 0; off >>= 1)
        for (int m = 0; m < 4; ++m) d[m] += __shfl_down(d[m], off, 64);
    if (lane == 0) for (int m = 0; m < 4; ++m) dred[m][wid] = d[m];
    __syncthreads();
    if (t == 0)
        for (int m = 0; m < 4; ++m)
            ws[WS_MOM + bid * 4 + m] = dred[m][0] + dred[m][1] + dred[m][2] + dred[m][3];
}

// k3: fused row-dots over x and u
__global__ void k3(const float* __restrict__ x, const float* __restrict__ u,
                   float* __restrict__ ws) {
    const int bid = blockIdx.x;   // 128: b*16+g
    const int b = bid >> 4, g = bid & 15;
    const int t = threadIdx.x;    // 256
    const int c0 = g * 16;
    __shared__ float eql[NN], ekl[NN], maql[NN], makl[NN];
    __shared__ float wv8[16][8][4];
    __shared__ float accw[2][4];
    const float* st = ws + WS_STAT + b * STAT_STRIDE;
    for (int j = 0; j < 4; ++j) {
        int n = t + 256 * j;
        eql[n]  = st[ST_EQ + n];
        ekl[n]  = st[ST_EK + n];
        maql[n] = ws[WS_MAQ + b * NN + n];
        makl[n] = ws[WS_MAK + b * NN + n];
    }
    __syncthreads();
    const float* xb = x + ((size_t)b * NC + c0) * NN;
    const float* ub = u + ((size_t)b * NC + c0) * NN;
    float x2a = 0.f, uua = 0.f;
    const int wid = t >> 6, lane = t & 63;
    for (int c = 0; c < 16; ++c) {
        float d[8] = {0.f, 0.f, 0.f, 0.f, 0.f, 0.f, 0.f, 0.f};
        for (int j = 0; j < 4; ++j) {
            int n = t + 256 * j;
            float xv = xb[c * NN + n], uv = ub[c * NN + n];
            float e = eql[n], kk = ekl[n], ma = maql[n], mk = makl[n];
            d[0] += xv * e;   // xe
            d[1] += xv * kk;  // xk
            d[2] += uv;       // Vsu
            d[3] += uv * e;   // Ue
            d[4] += uv * kk;  // Veu
            d[5] += xv * ma;  // caq
            d[6] += xv * mk;  // cak
            d[7] += uv * mk;  // cuak
            x2a += xv * xv;
            uua += uv * uv;
        }
        for (int off = 32; off > 0; off >>= 1)
            for (int m = 0; m < 8; ++m) d[m] += __shfl_down(d[m], off, 64);
        if (lane == 0) for (int m = 0; m < 8; ++m) wv8[c][m][wid] = d[m];
    }
    for (int off = 32; off > 0; off >>= 1) {
        x2a += __shfl_down(x2a, off, 64);
        uua += __shfl_down(uua, off, 64);
    }
    if (lane == 0) { accw[0][wid] = x2a; accw[1][wid] = uua; }
    __syncthreads();
    if (t < 16) {
        int c = t;
        float v[8];
        for (int m = 0; m < 8; ++m)
            v[m] = wv8[c][m][0] + wv8[c][m][1] + wv8[c][m][2] + wv8[c][m][3];
        ws[WS_XE   + b * NC + c0 + c] = v[0];
        ws[WS_XK   + b * NC + c0 + c] = v[1];
        ws[WS_VSU  + b * NC + c0 + c] = v[2];
        ws[WS_UE   + b * NC + c0 + c] = v[3];
        ws[WS_VEU  + b * NC + c0 + c] = v[4];
        ws[WS_CAQ  + b * NC + c0 + c] = v[5];
        ws[WS_CAK  + b * NC + c0 + c] = v[6];
        ws[WS_CUAK + b * NC + c0 + c] = v[7];
    }
    if (t == 0) {
        ws[WS_SX2P + bid] = accw[0][0] + accw[0][1] + accw[0][2] + accw[0][3];
        ws[WS_UUP + bid]  = accw[1][0] + accw[1][1] + accw[1][2] + accw[1][3];
    }
}

// ksv: Sv/Sve matvec (coalesced float4) + per-block T1/T2 partials for d2
__global__ void ksv(const float* __restrict__ Wv, const float* __restrict__ bv,
                    float* __restrict__ ws) {
    const int bid = blockIdx.x;          // 64: b*8 + oc
    const int b = bid >> 3, oc = bid & 7;
    const int t = threadIdx.x;           // 256
    const int o_sub = t >> 3, ks = t & 7;
    const int o = oc * 32 + o_sub;
    __shared__ float sxl[NC], xel[NC];
    __shared__ float T1s[32], T2s[32];
    sxl[t] = ws[WS_SX + b * NC + t];
    xel[t] = ws[WS_XE + b * NC + t];
    __syncthreads();
    float Seq = 0.f, Sek = 0.f, Sek2 = 0.f;
    for (int q = 0; q < 4; ++q) {
        Seq  += ws[WS_MOM + (b * 4 + q) * 4 + 0];
        Sek  += ws[WS_MOM + (b * 4 + q) * 4 + 1];
        Sek2 += ws[WS_MOM + (b * 4 + q) * 4 + 2];
    }
    const float cq = ws[WS_CQ], ck = ws[WS_CK];
    float wsx = 0.f, wxe = 0.f;
    const float4* wrow = (const float4*)(Wv + (size_t)o * NC);
#pragma unroll
    for (int i = 0; i < 8; ++i) {
        float4 w4 = wrow[i * 8 + ks];
        int k = i * 32 + ks * 4;
        wsx += w4.x * sxl[k] + w4.y * sxl[k + 1] + w4.z * sxl[k + 2] + w4.w * sxl[k + 3];
        wxe += w4.x * xel[k] + w4.y * xel[k + 1] + w4.z * xel[k + 2] + w4.w * xel[k + 3];
    }
    for (int off = 4; off > 0; off >>= 1) {
        wsx += __shfl_down(wsx, off, 8);
        wxe += __shfl_down(wxe, off, 8);
    }
    if (ks == 0) {
        float bvc = bv[o];
        float Sv  = wsx + (float)NN * bvc;
        float SvL = wsx;
        float Sve = wxe + bvc * Seq;
        float* st = ws + WS_STAT + b * STAT_STRIDE;
        st[ST_SV + o] = Sv; st[ST_SVE + o] = Sve;
        float A = 2.f * Sve - bvc * Seq - cq * Sv;
        float sx = sxl[o];
        float xk = ws[WS_XK + b * NC + o];
        float xkL = xk - ck * sx;
        float T1c = A * sx + Sv * xkL + SvL * xk;
        float SP  = Sek - (float)NN * ck;
        float SP2 = Sek2 - 2.f * ck * Sek + (float)NN * ck * ck;
        float SPQ = Sek2 - ck * Sek;
        float T2c = (float)NN * A * A + Sv * Sv * SP2 + SvL * SvL * Sek2
                  + 2.f * A * Sv * SP + 2.f * A * SvL * Sek + 2.f * Sv * SvL * SPQ;
        T1s[o_sub] = T1c; T2s[o_sub] = T2c;
    }
    __syncthreads();
    if (t == 0) {
        float t1 = 0.f, t2 = 0.f;
        for (int i = 0; i < 32; ++i) { t1 += T1s[i]; t2 += T2s[i]; }
        ws[WS_T1P + bid] = t1;
        ws[WS_T2P + bid] = t2;
    }
}

// kiter: closed-form 5-term vjp/trace recursion; Wv column-cached in registers.
__global__ __launch_bounds__(1024, 4) void kiter(
        const float* __restrict__ Wv, const float* __restrict__ bv,
        const float* __restrict__ gamma, float* __restrict__ ws,
        float* __restrict__ out) {
    const int b = blockIdx.x;            // 8
    const int t = threadIdx.x;           // 1024
    const int o = t & 255, q = t >> 8;
    const int wid4 = o >> 6, lane = t & 63;
    __shared__ float VV[2 * NC];         // interleaved Vs/Ve
    __shared__ float redPR[2 * 1024];
    __shared__ float dred[9][4];
    __shared__ float sge;
    // gamma_eff from T1/T2/Sx2 partials (block-redundant, t==0)
    if (t == 0) {
        float dd = 0.f, xx = 0.f;
        float inv = gamma[0] * (1.f / (float)NN);
        for (int bb = 0; bb < NB; ++bb) {
            float Sx2 = 0.f;
            for (int g = 0; g < 16; ++g) Sx2 += ws[WS_SX2P + bb * 16 + g];
            float T1 = 0.f, T2 = 0.f;
            for (int g = 0; g < 8; ++g) { T1 += ws[WS_T1P + bb * 8 + g]; T2 += ws[WS_T2P + bb * 8 + g]; }
            dd += Sx2 + 2.f * inv * T1 + inv * inv * T2;
            xx += Sx2;
        }
        float lip = sqrtf(dd / xx);
        float ge = gamma[0] * ((lip > 0.9f) ? (0.9f / lip) : 1.f);
        sge = ge;
        if (b == 0) ws[WS_GE] = ge;
    }
    __syncthreads();
    const float s = sge * (1.f / (float)NN);
    // Wv columns into registers, scaled by s: wreg[i] = s*Wv[q*64+i][o]
    float wreg[64];
#pragma unroll
    for (int i = 0; i < 64; ++i)
        wreg[i] = s * Wv[(size_t)(q * 64 + i) * NC + o];
    // per-channel constants (t<256)
    float Svl_r = 0.f, sxl_r = 0.f, xkl_r = 0.f, caql_r = 0.f, cakl_r = 0.f,
          Uel_r = 0.f, Vsul_r = 0.f, bvl_r = 0.f, aql_r = 0.f, akl_r = 0.f,
          veu_r = 0.f, cuak_r = 0.f, vsreg = 0.f, vereg = 0.f;
    if (t < 256) {
        const float* st = ws + WS_STAT + b * STAT_STRIDE;
        Svl_r  = st[ST_SV + t];
        sxl_r  = ws[WS_SX   + b * NC + t];
        xkl_r  = ws[WS_XK   + b * NC + t];
        caql_r = ws[WS_CAQ  + b * NC + t];
        cakl_r = ws[WS_CAK  + b * NC + t];
        Uel_r  = ws[WS_UE   + b * NC + t];
        Vsul_r = ws[WS_VSU  + b * NC + t];
        veu_r  = ws[WS_VEU  + b * NC + t];
        cuak_r = ws[WS_CUAK + b * NC + t];
        aql_r  = ws[WS_AQ + t];
        akl_r  = ws[WS_AK + t];
        bvl_r  = bv[t];
        vsreg = Vsul_r; vereg = veu_r;
        VV[2 * t] = vsreg; VV[2 * t + 1] = vereg;
    }
    float Seq = 0.f, Sek = 0.f, Sekq = 0.f;
    for (int qq = 0; qq < 4; ++qq) {
        Seq  += ws[WS_MOM + (b * 4 + qq) * 4 + 0];
        Sek  += ws[WS_MOM + (b * 4 + qq) * 4 + 1];
        Sekq += ws[WS_MOM + (b * 4 + qq) * 4 + 3];
    }
    float uu = 0.f;
    for (int g = 0; g < 16; ++g) uu += ws[WS_UUP + b * 16 + g];
    __syncthreads();
    // prologue dots
    if (t < 256) {
        float d[8] = {Svl_r * cuak_r, aql_r * Vsul_r, akl_r * Vsul_r, akl_r * Uel_r,
                      Svl_r * Vsul_r, Svl_r * veu_r,  Svl_r * aql_r,  Svl_r * akl_r};
        for (int off = 32; off > 0; off >>= 1)
            for (int m = 0; m < 8; ++m) d[m] += __shfl_down(d[m], off, 64);
        if (lane == 0) for (int m = 0; m < 8; ++m) dred[m][wid4] = d[m];
    }
    __syncthreads();
    float g2a = 0.f, aqVsu = 0.f, akVsu = 0.f, akUe = 0.f, SvVsu = 0.f, SvVeu = 0.f,
          Svaq = 0.f, Svak = 0.f;
    if (t < 256) {
        g2a   = dred[0][0] + dred[0][1] + dred[0][2] + dred[0][3];
        aqVsu = dred[1][0] + dred[1][1] + dred[1][2] + dred[1][3];
        akVsu = dred[2][0] + dred[2][1] + dred[2][2] + dred[2][3];
        akUe  = dred[3][0] + dred[3][1] + dred[3][2] + dred[3][3];
        SvVsu = dred[4][0] + dred[4][1] + dred[4][2] + dred[4][3];
        SvVeu = dred[5][0] + dred[5][1] + dred[5][2] + dred[5][3];
        Svaq  = dred[6][0] + dred[6][1] + dred[6][2] + dred[6][3];
        Svak  = dred[7][0] + dred[7][1] + dred[7][2] + dred[7][3];
    }
    __syncthreads();
    const float lam = 1.f + s * Svak;
    float alpha = 1.f, beta = 0.f, gam = 0.f;
    float SxAcc = 0.f, XkAcc = 0.f, CakAcc = 0.f;
    float dot = uu, tr = 0.f;
    const float coef[5] = {1.f, -0.5f, 1.f / 3.f, -0.25f, 0.2f};
#pragma unroll
    for (int j = 0; j < 5; ++j) {
        // matvec: all 1024 threads, registers x LDS-broadcast
        float pa = 0.f, ra = 0.f;
#pragma unroll
        for (int i = 0; i < 64; ++i) {
            float2 vv = ((const float2*)VV)[q * 64 + i];
            pa += wreg[i] * vv.x;
            ra += wreg[i] * vv.y;
        }
        redPR[2 * t] = pa; redPR[2 * t + 1] = ra;
        __syncthreads();
        float Pv = 0.f, Rv = 0.f;
        if (t < 256) {
            Pv = redPR[2 * t] + redPR[2 * (t + 256)] + redPR[2 * (t + 512)] + redPR[2 * (t + 768)];
            Rv = redPR[2 * t + 1] + redPR[2 * (t + 256) + 1] + redPR[2 * (t + 512) + 1] + redPR[2 * (t + 768) + 1];
            float d[9];
            d[0] = Svl_r * Pv;    // svP
            d[1] = Svl_r * Rv;    // svR
            d[2] = bvl_r * vsreg; // bvVs
            d[3] = sxl_r * Pv;    // sxP
            d[4] = xkl_r * Pv;    // xkP
            d[5] = caql_r * Pv;   // caqP
            d[6] = cakl_r * Pv;   // cakP
            d[7] = Uel_r * Pv;    // ueP
            d[8] = Vsul_r * Rv;   // vsuR
            for (int off = 32; off > 0; off >>= 1)
                for (int m = 0; m < 9; ++m) d[m] += __shfl_down(d[m], off, 64);
            if (lane == 0) for (int m = 0; m < 9; ++m) dred[m][wid4] = d[m];
        }
        __syncthreads();
        if (t < 256) {
            float sm[9];
            for (int m = 0; m < 9; ++m) sm[m] = dred[m][0] + dred[m][1] + dred[m][2] + dred[m][3];
            const float svP = sm[0], svR = sm[1], bvVs = sm[2], sxP = sm[3], xkP = sm[4],
                        caqP = sm[5], cakP = sm[6], ueP = sm[7], vsuR = sm[8];
            const float sB = s * bvVs;
            float St  = s * (alpha * SvVsu + beta * (float)NN + gam * Seq  + Svaq * SxAcc);
            float tek = s * (alpha * SvVeu + beta * Sek        + gam * Sekq + Svaq * XkAcc);
            float uta = s * (alpha * g2a   + beta * akVsu      + gam * akUe + Svaq * CakAcc);
            dot += ueP + caqP + sB * aqVsu + uta + vsuR;
            tr  += coef[j] * dot;
            float nVs = vsreg + Pv * Seq  + aql_r * (sxP + (float)NN * sB) + akl_r * St  + Rv * (float)NN;
            float nVe = vereg + Pv * Sekq + aql_r * (xkP + sB * Sek)       + akl_r * tek + Rv * Sek;
            vsreg = nVs; vereg = nVe;
            VV[2 * t] = nVs; VV[2 * t + 1] = nVe;
            SxAcc  = lam * SxAcc  + sxP;
            XkAcc  = lam * XkAcc  + xkP;
            CakAcc = lam * CakAcc + cakP;
            beta = lam * beta + Svaq * sB + svR;
            gam  = lam * gam + svP;
            alpha *= lam;
        }
        __syncthreads();
    }
    if (t == 0) out[2097152 + b] = tr;
}

// Output 0: 2x + (ge/N)(Sve[c] + ek[m]*Sv[c]); ge from ws (written by kiter)
__global__ void kout0(const float* __restrict__ x, const float* __restrict__ ws,
                      float* __restrict__ out) {
    int bid = blockIdx.x;            // 2048: b*256 + c
    int b = bid >> 8, c = bid & 255, t = threadIdx.x;  // 256
    float ge = ws[WS_GE] * (1.f / (float)NN);
    const float* st = ws + WS_STAT + b * STAT_STRIDE;
    float sv = st[ST_SV + c], sve = st[ST_SVE + c];
    float4 ek4 = ((const float4*)(st + ST_EK))[t];
    size_t i4 = (size_t)bid * 256 + t;
    float4 x4 = ((const float4*)x)[i4];
    float4 o;
    o.x = 2.f * x4.x + ge * (sve + ek4.x * sv);
    o.y = 2.f * x4.y + ge * (sve + ek4.y * sv);
    o.z = 2.f * x4.z + ge * (sve + ek4.z * sv);
    o.w = 2.f * x4.w + ge * (sve + ek4.w * sv);
    ((float4*)out)[i4] = o;
}

extern "C" void kernel_launch(void* const* d_in, const int* in_sizes, int n_in,
                              void* d_out, int out_size, void* d_ws, size_t ws_size,
                              hipStream_t stream) {
    const float* x     = (const float*)d_in[0];
    const float* Wq    = (const float*)d_in[1];
    const float* bq    = (const float*)d_in[2];
    const float* Wk    = (const float*)d_in[3];
    const float* bk    = (const float*)d_in[4];
    const float* Wc    = (const float*)d_in[5];
    const float* Wv    = (const float*)d_in[6];
    const float* bv    = (const float*)d_in[7];
    const float* gamma = (const float*)d_in[8];
    const float* u     = (const float*)d_in[9];
    float* out = (float*)d_out;
    float* ws  = (float*)d_ws;

    k1   <<<dim3(128),  dim3(256),  0, stream>>>(x, u, Wq, bq, Wk, bk, Wc, ws);
    k2   <<<dim3(32),   dim3(256),  0, stream>>>(ws);
    k3   <<<dim3(128),  dim3(256),  0, stream>>>(x, u, ws);
    ksv  <<<dim3(64),   dim3(256),  0, stream>>>(Wv, bv, ws);
    kiter<<<dim3(8),    dim3(1024), 0, stream>>>(Wv, bv, gamma, ws, out);
    kout0<<<dim3(2048), dim3(256),  0, stream>>>(x, ws, out);
}

// Round 6
// 134.018 us; speedup vs baseline: 1.0731x; 1.0731x over previous
//
#include <hip/hip_runtime.h>
#include <math.h>

// Problem constants
#define NB 8      // batch
#define NC 256    // channels
#define NN 1024   // spatial H*W
#define NICH 64   // inter channels

// ws layout (float offsets)
#define WS_AQ    0        // [256]
#define WS_AK    256      // [256]
#define WS_CQ    512
#define WS_CK    513
#define WS_GE    514
#define WS_MOM   520      // [32][4]: Seq,Sek,Sek2,Sekq partials per (b,qchunk)
#define WS_SX    1024     // [8][256]
#define WS_XE    3072     // [8][256]
#define WS_XK    5120     // [8][256]
#define WS_SX2P  7168     // [128]
#define WS_UUP   7296     // [128]
#define WS_T1P   7424     // [64]
#define WS_T2P   7488     // [64]
#define WS_VSU   7680     // [8][256]  u·1
#define WS_UE    9728     // [8][256]  u·eq
#define WS_VEU   11776    // [8][256]  u·ek
#define WS_CAQ   13824    // [8][256]  x·(u^T aq)
#define WS_CAK   15872    // [8][256]  x·(u^T ak)
#define WS_CUAK  17920    // [8][256]  u·(u^T ak)
#define WS_STAT  20480    // [8] stride 2560: eq,ek,Sv,Sve
#define STAT_STRIDE 2560
#define ST_EQ    0        // [1024]
#define ST_EK    1024     // [1024]
#define ST_SV    2048     // [256]
#define ST_SVE   2304     // [256]
#define WS_MAQ   40960    // [8][1024]  u^T aq
#define WS_MAK   49152    // [8][1024]  u^T ak
#define WS_EQP   57344    // [128][1024]
#define WS_EKP   188416   // [128][1024]
#define WS_MAQP  319488   // [128][1024]
#define WS_MAKP  450560   // [128][1024] ends 581632 floats

// k1: per (b,16-ch group): eq/ek partials and maq/mak partials over n, sx per channel.
__global__ void k1(const float* __restrict__ x, const float* __restrict__ u,
                   const float* __restrict__ Wq, const float* __restrict__ bq,
                   const float* __restrict__ Wk, const float* __restrict__ bk,
                   const float* __restrict__ Wc, float* __restrict__ ws) {
    const int bid = blockIdx.x;          // 128: b*16+g
    const int b = bid >> 4, g = bid & 15;
    const int t = threadIdx.x;           // 256
    const int c0 = g * 16;
    __shared__ float aql[16], akl[16];
    __shared__ float sxw[16][4];
    if (t < 16) {
        float a = 0.f, k = 0.f;
        for (int o = 0; o < NICH; ++o) {
            a += Wc[o] * Wq[o * NC + c0 + t];
            k += Wc[NICH + o] * Wk[o * NC + c0 + t];
        }
        aql[t] = a; akl[t] = k;
        ws[WS_AQ + c0 + t] = a;
        ws[WS_AK + c0 + t] = k;
    }
    if (t == 16) { float s = 0.f; for (int o = 0; o < 64; ++o) s += Wc[o] * bq[o]; ws[WS_CQ] = s; }
    if (t == 17) { float s = 0.f; for (int o = 0; o < 64; ++o) s += Wc[NICH + o] * bk[o]; ws[WS_CK] = s; }
    __syncthreads();
    const float* xb = x + ((size_t)b * NC + c0) * NN;
    const float* ub = u + ((size_t)b * NC + c0) * NN;
    float eqp[4] = {0.f, 0.f, 0.f, 0.f}, ekp[4] = {0.f, 0.f, 0.f, 0.f};
    float map[4] = {0.f, 0.f, 0.f, 0.f}, mkp[4] = {0.f, 0.f, 0.f, 0.f};
    const int wid = t >> 6, lane = t & 63;
    for (int c = 0; c < 16; ++c) {
        float a = aql[c], k = akl[c];
        float xs = 0.f;
#pragma unroll
        for (int jj = 0; jj < 4; ++jj) {
            float xv = xb[c * NN + t + 256 * jj];
            float uv = ub[c * NN + t + 256 * jj];
            eqp[jj] += a * xv; ekp[jj] += k * xv;
            map[jj] += a * uv; mkp[jj] += k * uv;
            xs += xv;
        }
        for (int off = 32; off > 0; off >>= 1) xs += __shfl_down(xs, off, 64);
        if (lane == 0) sxw[c][wid] = xs;
    }
    __syncthreads();
    if (t < 16) ws[WS_SX + b * NC + c0 + t] = sxw[t][0] + sxw[t][1] + sxw[t][2] + sxw[t][3];
    size_t pb = (size_t)bid * 1024;
#pragma unroll
    for (int jj = 0; jj < 4; ++jj) {
        ws[WS_EQP  + pb + t + 256 * jj] = eqp[jj];
        ws[WS_EKP  + pb + t + 256 * jj] = ekp[jj];
        ws[WS_MAQP + pb + t + 256 * jj] = map[jj];
        ws[WS_MAKP + pb + t + 256 * jj] = mkp[jj];
    }
}

// k2: finalize eq/ek + maq/mak, 4 moments (Seq, Sek, Sek2, Sekq)
__global__ void k2(float* __restrict__ ws) {
    const int bid = blockIdx.x;      // 32: b*4+qc
    const int b = bid >> 2, qc = bid & 3;
    const int t = threadIdx.x;       // 256
    const int n = qc * 256 + t;
    const float cq = ws[WS_CQ], ck = ws[WS_CK];
    float e = 0.f, k = 0.f, ma = 0.f, mk = 0.f;
    for (int g = 0; g < 16; ++g) {
        size_t pb = (size_t)(b * 16 + g) * 1024 + n;
        e  += ws[WS_EQP  + pb];
        k  += ws[WS_EKP  + pb];
        ma += ws[WS_MAQP + pb];
        mk += ws[WS_MAKP + pb];
    }
    e += cq; k += ck;
    float* st = ws + WS_STAT + b * STAT_STRIDE;
    st[ST_EQ + n] = e;
    st[ST_EK + n] = k;
    ws[WS_MAQ + b * NN + n] = ma;
    ws[WS_MAK + b * NN + n] = mk;
    float d[4] = {e, k, k * k, e * k};
    __shared__ float dred[4][4];
    const int wid = t >> 6, lane = t & 63;
    for (int off = 32; off > 0; off >>= 1)
        for (int m = 0; m < 4; ++m) d[m] += __shfl_down(d[m], off, 64);
    if (lane == 0) for (int m = 0; m < 4; ++m) dred[m][wid] = d[m];
    __syncthreads();
    if (t == 0)
        for (int m = 0; m < 4; ++m)
            ws[WS_MOM + bid * 4 + m] = dred[m][0] + dred[m][1] + dred[m][2] + dred[m][3];
}

// k3: fused row-dots over x and u
__global__ void k3(const float* __restrict__ x, const float* __restrict__ u,
                   float* __restrict__ ws) {
    const int bid = blockIdx.x;   // 128: b*16+g
    const int b = bid >> 4, g = bid & 15;
    const int t = threadIdx.x;    // 256
    const int c0 = g * 16;
    __shared__ float eql[NN], ekl[NN], maql[NN], makl[NN];
    __shared__ float wv8[16][8][4];
    __shared__ float accw[2][4];
    const float* st = ws + WS_STAT + b * STAT_STRIDE;
    for (int j = 0; j < 4; ++j) {
        int n = t + 256 * j;
        eql[n]  = st[ST_EQ + n];
        ekl[n]  = st[ST_EK + n];
        maql[n] = ws[WS_MAQ + b * NN + n];
        makl[n] = ws[WS_MAK + b * NN + n];
    }
    __syncthreads();
    const float* xb = x + ((size_t)b * NC + c0) * NN;
    const float* ub = u + ((size_t)b * NC + c0) * NN;
    float x2a = 0.f, uua = 0.f;
    const int wid = t >> 6, lane = t & 63;
    for (int c = 0; c < 16; ++c) {
        float d[8] = {0.f, 0.f, 0.f, 0.f, 0.f, 0.f, 0.f, 0.f};
        for (int j = 0; j < 4; ++j) {
            int n = t + 256 * j;
            float xv = xb[c * NN + n], uv = ub[c * NN + n];
            float e = eql[n], kk = ekl[n], ma = maql[n], mk = makl[n];
            d[0] += xv * e;   // xe
            d[1] += xv * kk;  // xk
            d[2] += uv;       // Vsu
            d[3] += uv * e;   // Ue
            d[4] += uv * kk;  // Veu
            d[5] += xv * ma;  // caq
            d[6] += xv * mk;  // cak
            d[7] += uv * mk;  // cuak
            x2a += xv * xv;
            uua += uv * uv;
        }
        for (int off = 32; off > 0; off >>= 1)
            for (int m = 0; m < 8; ++m) d[m] += __shfl_down(d[m], off, 64);
        if (lane == 0) for (int m = 0; m < 8; ++m) wv8[c][m][wid] = d[m];
    }
    for (int off = 32; off > 0; off >>= 1) {
        x2a += __shfl_down(x2a, off, 64);
        uua += __shfl_down(uua, off, 64);
    }
    if (lane == 0) { accw[0][wid] = x2a; accw[1][wid] = uua; }
    __syncthreads();
    if (t < 16) {
        int c = t;
        float v[8];
        for (int m = 0; m < 8; ++m)
            v[m] = wv8[c][m][0] + wv8[c][m][1] + wv8[c][m][2] + wv8[c][m][3];
        ws[WS_XE   + b * NC + c0 + c] = v[0];
        ws[WS_XK   + b * NC + c0 + c] = v[1];
        ws[WS_VSU  + b * NC + c0 + c] = v[2];
        ws[WS_UE   + b * NC + c0 + c] = v[3];
        ws[WS_VEU  + b * NC + c0 + c] = v[4];
        ws[WS_CAQ  + b * NC + c0 + c] = v[5];
        ws[WS_CAK  + b * NC + c0 + c] = v[6];
        ws[WS_CUAK + b * NC + c0 + c] = v[7];
    }
    if (t == 0) {
        ws[WS_SX2P + bid] = accw[0][0] + accw[0][1] + accw[0][2] + accw[0][3];
        ws[WS_UUP + bid]  = accw[1][0] + accw[1][1] + accw[1][2] + accw[1][3];
    }
}

// ksv: Sv/Sve matvec (coalesced float4) + per-block T1/T2 partials for d2
__global__ void ksv(const float* __restrict__ Wv, const float* __restrict__ bv,
                    float* __restrict__ ws) {
    const int bid = blockIdx.x;          // 64: b*8 + oc
    const int b = bid >> 3, oc = bid & 7;
    const int t = threadIdx.x;           // 256
    const int o_sub = t >> 3, ks = t & 7;
    const int o = oc * 32 + o_sub;
    __shared__ float sxl[NC], xel[NC];
    __shared__ float T1s[32], T2s[32];
    sxl[t] = ws[WS_SX + b * NC + t];
    xel[t] = ws[WS_XE + b * NC + t];
    __syncthreads();
    float Seq = 0.f, Sek = 0.f, Sek2 = 0.f;
    for (int q = 0; q < 4; ++q) {
        Seq  += ws[WS_MOM + (b * 4 + q) * 4 + 0];
        Sek  += ws[WS_MOM + (b * 4 + q) * 4 + 1];
        Sek2 += ws[WS_MOM + (b * 4 + q) * 4 + 2];
    }
    const float cq = ws[WS_CQ], ck = ws[WS_CK];
    float wsx = 0.f, wxe = 0.f;
    const float4* wrow = (const float4*)(Wv + (size_t)o * NC);
#pragma unroll
    for (int i = 0; i < 8; ++i) {
        float4 w4 = wrow[i * 8 + ks];
        int k = i * 32 + ks * 4;
        wsx += w4.x * sxl[k] + w4.y * sxl[k + 1] + w4.z * sxl[k + 2] + w4.w * sxl[k + 3];
        wxe += w4.x * xel[k] + w4.y * xel[k + 1] + w4.z * xel[k + 2] + w4.w * xel[k + 3];
    }
    for (int off = 4; off > 0; off >>= 1) {
        wsx += __shfl_down(wsx, off, 8);
        wxe += __shfl_down(wxe, off, 8);
    }
    if (ks == 0) {
        float bvc = bv[o];
        float Sv  = wsx + (float)NN * bvc;
        float SvL = wsx;
        float Sve = wxe + bvc * Seq;
        float* st = ws + WS_STAT + b * STAT_STRIDE;
        st[ST_SV + o] = Sv; st[ST_SVE + o] = Sve;
        float A = 2.f * Sve - bvc * Seq - cq * Sv;
        float sx = sxl[o];
        float xk = ws[WS_XK + b * NC + o];
        float xkL = xk - ck * sx;
        float T1c = A * sx + Sv * xkL + SvL * xk;
        float SP  = Sek - (float)NN * ck;
        float SP2 = Sek2 - 2.f * ck * Sek + (float)NN * ck * ck;
        float SPQ = Sek2 - ck * Sek;
        float T2c = (float)NN * A * A + Sv * Sv * SP2 + SvL * SvL * Sek2
                  + 2.f * A * Sv * SP + 2.f * A * SvL * Sek + 2.f * Sv * SvL * SPQ;
        T1s[o_sub] = T1c; T2s[o_sub] = T2c;
    }
    __syncthreads();
    if (t == 0) {
        float t1 = 0.f, t2 = 0.f;
        for (int i = 0; i < 32; ++i) { t1 += T1s[i]; t2 += T2s[i]; }
        ws[WS_T1P + bid] = t1;
        ws[WS_T2P + bid] = t2;
    }
}

// kiter: closed-form 5-term vjp/trace recursion.
// Wv re-read from global each iteration (L2-resident, coalesced) — NO per-thread
// Wv cache: a 64-element thread-local array spilled to scratch in round 4/5
// (VGPR_Count=64 < required) and cost 90us. ~30 VGPRs now, no spill.
__global__ void kiter(
        const float* __restrict__ Wv, const float* __restrict__ bv,
        const float* __restrict__ gamma, float* __restrict__ ws,
        float* __restrict__ out) {
    const int b = blockIdx.x;            // 8
    const int t = threadIdx.x;           // 1024
    const int o = t & 255, q = t >> 8;
    const int wid4 = o >> 6, lane = t & 63;
    __shared__ float VV[2 * NC];         // interleaved Vs/Ve
    __shared__ float redPR[2 * 1024];
    __shared__ float dred[9][4];
    __shared__ float gred[3][2];
    __shared__ float sge;
    // gamma_eff: dd/xx are LINEAR in the partials -> 3 global sums, wave-parallel
    {
        float a = 0.f, b1 = 0.f, c1 = 0.f;
        if (t < 128) a = ws[WS_SX2P + t];
        if (t < 64) { b1 = ws[WS_T1P + t]; c1 = ws[WS_T2P + t]; }
        for (int off = 32; off > 0; off >>= 1) {
            a  += __shfl_down(a,  off, 64);
            b1 += __shfl_down(b1, off, 64);
            c1 += __shfl_down(c1, off, 64);
        }
        if (t < 128 && lane == 0) { gred[0][t >> 6] = a; gred[1][t >> 6] = b1; gred[2][t >> 6] = c1; }
    }
    __syncthreads();
    if (t == 0) {
        float S1 = gred[0][0] + gred[0][1];
        float T1 = gred[1][0] + gred[1][1];
        float T2 = gred[2][0] + gred[2][1];
        float inv = gamma[0] * (1.f / (float)NN);
        float dd = S1 + 2.f * inv * T1 + inv * inv * T2;
        float lip = sqrtf(dd / S1);
        float ge = gamma[0] * ((lip > 0.9f) ? (0.9f / lip) : 1.f);
        sge = ge;
        if (b == 0) ws[WS_GE] = ge;
    }
    __syncthreads();
    const float s = sge * (1.f / (float)NN);
    // per-channel constants (t<256)
    float Svl_r = 0.f, sxl_r = 0.f, xkl_r = 0.f, caql_r = 0.f, cakl_r = 0.f,
          Uel_r = 0.f, Vsul_r = 0.f, bvl_r = 0.f, aql_r = 0.f, akl_r = 0.f,
          veu_r = 0.f, cuak_r = 0.f, vsreg = 0.f, vereg = 0.f;
    if (t < 256) {
        const float* st = ws + WS_STAT + b * STAT_STRIDE;
        Svl_r  = st[ST_SV + t];
        sxl_r  = ws[WS_SX   + b * NC + t];
        xkl_r  = ws[WS_XK   + b * NC + t];
        caql_r = ws[WS_CAQ  + b * NC + t];
        cakl_r = ws[WS_CAK  + b * NC + t];
        Uel_r  = ws[WS_UE   + b * NC + t];
        Vsul_r = ws[WS_VSU  + b * NC + t];
        veu_r  = ws[WS_VEU  + b * NC + t];
        cuak_r = ws[WS_CUAK + b * NC + t];
        aql_r  = ws[WS_AQ + t];
        akl_r  = ws[WS_AK + t];
        bvl_r  = bv[t];
        vsreg = Vsul_r; vereg = veu_r;
        VV[2 * t] = vsreg; VV[2 * t + 1] = vereg;
    }
    float Seq = 0.f, Sek = 0.f, Sekq = 0.f;
    for (int qq = 0; qq < 4; ++qq) {
        Seq  += ws[WS_MOM + (b * 4 + qq) * 4 + 0];
        Sek  += ws[WS_MOM + (b * 4 + qq) * 4 + 1];
        Sekq += ws[WS_MOM + (b * 4 + qq) * 4 + 3];
    }
    float uu = 0.f;
    for (int g = 0; g < 16; ++g) uu += ws[WS_UUP + b * 16 + g];
    __syncthreads();
    // prologue dots
    if (t < 256) {
        float d[8] = {Svl_r * cuak_r, aql_r * Vsul_r, akl_r * Vsul_r, akl_r * Uel_r,
                      Svl_r * Vsul_r, Svl_r * veu_r,  Svl_r * aql_r,  Svl_r * akl_r};
        for (int off = 32; off > 0; off >>= 1)
            for (int m = 0; m < 8; ++m) d[m] += __shfl_down(d[m], off, 64);
        if (lane == 0) for (int m = 0; m < 8; ++m) dred[m][wid4] = d[m];
    }
    __syncthreads();
    float g2a = 0.f, aqVsu = 0.f, akVsu = 0.f, akUe = 0.f, SvVsu = 0.f, SvVeu = 0.f,
          Svaq = 0.f, Svak = 0.f;
    if (t < 256) {
        g2a   = dred[0][0] + dred[0][1] + dred[0][2] + dred[0][3];
        aqVsu = dred[1][0] + dred[1][1] + dred[1][2] + dred[1][3];
        akVsu = dred[2][0] + dred[2][1] + dred[2][2] + dred[2][3];
        akUe  = dred[3][0] + dred[3][1] + dred[3][2] + dred[3][3];
        SvVsu = dred[4][0] + dred[4][1] + dred[4][2] + dred[4][3];
        SvVeu = dred[5][0] + dred[5][1] + dred[5][2] + dred[5][3];
        Svaq  = dred[6][0] + dred[6][1] + dred[6][2] + dred[6][3];
        Svak  = dred[7][0] + dred[7][1] + dred[7][2] + dred[7][3];
    }
    __syncthreads();
    const float lam = 1.f + s * Svak;
    float alpha = 1.f, beta = 0.f, gam = 0.f;
    float SxAcc = 0.f, XkAcc = 0.f, CakAcc = 0.f;
    float dot = uu, tr = 0.f;
    const float coef[5] = {1.f, -0.5f, 1.f / 3.f, -0.25f, 0.2f};
    const float* wbase = Wv + (size_t)(q * 64) * NC + o;   // coalesced row segments
    for (int j = 0; j < 5; ++j) {
        // matvec: 1024 threads, Wv streamed from global (L2-hit), VV LDS-broadcast
        float pa = 0.f, ra = 0.f;
#pragma unroll
        for (int i = 0; i < 64; ++i) {
            float w = wbase[(size_t)i * NC];
            float2 vv = ((const float2*)VV)[q * 64 + i];
            pa += w * vv.x;
            ra += w * vv.y;
        }
        redPR[2 * t] = pa; redPR[2 * t + 1] = ra;
        __syncthreads();
        float Pv = 0.f, Rv = 0.f;
        if (t < 256) {
            Pv = s * (redPR[2 * t] + redPR[2 * (t + 256)] + redPR[2 * (t + 512)] + redPR[2 * (t + 768)]);
            Rv = s * (redPR[2 * t + 1] + redPR[2 * (t + 256) + 1] + redPR[2 * (t + 512) + 1] + redPR[2 * (t + 768) + 1]);
            float d[9];
            d[0] = Svl_r * Pv;    // svP
            d[1] = Svl_r * Rv;    // svR
            d[2] = bvl_r * vsreg; // bvVs
            d[3] = sxl_r * Pv;    // sxP
            d[4] = xkl_r * Pv;    // xkP
            d[5] = caql_r * Pv;   // caqP
            d[6] = cakl_r * Pv;   // cakP
            d[7] = Uel_r * Pv;    // ueP
            d[8] = Vsul_r * Rv;   // vsuR
            for (int off = 32; off > 0; off >>= 1)
                for (int m = 0; m < 9; ++m) d[m] += __shfl_down(d[m], off, 64);
            if (lane == 0) for (int m = 0; m < 9; ++m) dred[m][wid4] = d[m];
        }
        __syncthreads();
        if (t < 256) {
            float sm[9];
            for (int m = 0; m < 9; ++m) sm[m] = dred[m][0] + dred[m][1] + dred[m][2] + dred[m][3];
            const float svP = sm[0], svR = sm[1], bvVs = sm[2], sxP = sm[3], xkP = sm[4],
                        caqP = sm[5], cakP = sm[6], ueP = sm[7], vsuR = sm[8];
            const float sB = s * bvVs;
            float St  = s * (alpha * SvVsu + beta * (float)NN + gam * Seq  + Svaq * SxAcc);
            float tek = s * (alpha * SvVeu + beta * Sek        + gam * Sekq + Svaq * XkAcc);
            float uta = s * (alpha * g2a   + beta * akVsu      + gam * akUe + Svaq * CakAcc);
            dot += ueP + caqP + sB * aqVsu + uta + vsuR;
            tr  += coef[j] * dot;
            float nVs = vsreg + Pv * Seq  + aql_r * (sxP + (float)NN * sB) + akl_r * St  + Rv * (float)NN;
            float nVe = vereg + Pv * Sekq + aql_r * (xkP + sB * Sek)       + akl_r * tek + Rv * Sek;
            vsreg = nVs; vereg = nVe;
            VV[2 * t] = nVs; VV[2 * t + 1] = nVe;
            SxAcc  = lam * SxAcc  + sxP;
            XkAcc  = lam * XkAcc  + xkP;
            CakAcc = lam * CakAcc + cakP;
            beta = lam * beta + Svaq * sB + svR;
            gam  = lam * gam + svP;
            alpha *= lam;
        }
        __syncthreads();
    }
    if (t == 0) out[2097152 + b] = tr;
}

// Output 0: 2x + (ge/N)(Sve[c] + ek[m]*Sv[c]); ge from ws (written by kiter)
__global__ void kout0(const float* __restrict__ x, const float* __restrict__ ws,
                      float* __restrict__ out) {
    int bid = blockIdx.x;            // 2048: b*256 + c
    int b = bid >> 8, c = bid & 255, t = threadIdx.x;  // 256
    float ge = ws[WS_GE] * (1.f / (float)NN);
    const float* st = ws + WS_STAT + b * STAT_STRIDE;
    float sv = st[ST_SV + c], sve = st[ST_SVE + c];
    float4 ek4 = ((const float4*)(st + ST_EK))[t];
    size_t i4 = (size_t)bid * 256 + t;
    float4 x4 = ((const float4*)x)[i4];
    float4 o;
    o.x = 2.f * x4.x + ge * (sve + ek4.x * sv);
    o.y = 2.f * x4.y + ge * (sve + ek4.y * sv);
    o.z = 2.f * x4.z + ge * (sve + ek4.z * sv);
    o.w = 2.f * x4.w + ge * (sve + ek4.w * sv);
    ((float4*)out)[i4] = o;
}

extern "C" void kernel_launch(void* const* d_in, const int* in_sizes, int n_in,
                              void* d_out, int out_size, void* d_ws, size_t ws_size,
                              hipStream_t stream) {
    const float* x     = (const float*)d_in[0];
    const float* Wq    = (const float*)d_in[1];
    const float* bq    = (const float*)d_in[2];
    const float* Wk    = (const float*)d_in[3];
    const float* bk    = (const float*)d_in[4];
    const float* Wc    = (const float*)d_in[5];
    const float* Wv    = (const float*)d_in[6];
    const float* bv    = (const float*)d_in[7];
    const float* gamma = (const float*)d_in[8];
    const float* u     = (const float*)d_in[9];
    float* out = (float*)d_out;
    float* ws  = (float*)d_ws;

    k1   <<<dim3(128),  dim3(256),  0, stream>>>(x, u, Wq, bq, Wk, bk, Wc, ws);
    k2   <<<dim3(32),   dim3(256),  0, stream>>>(ws);
    k3   <<<dim3(128),  dim3(256),  0, stream>>>(x, u, ws);
    ksv  <<<dim3(64),   dim3(256),  0, stream>>>(Wv, bv, ws);
    kiter<<<dim3(8),    dim3(1024), 0, stream>>>(Wv, bv, gamma, ws, out);
    kout0<<<dim3(2048), dim3(256),  0, stream>>>(x, ws, out);
}

// Round 7
// 89.141 us; speedup vs baseline: 1.6133x; 1.5034x over previous
//
#include <hip/hip_runtime.h>
#include <math.h>

// Problem constants
#define NB 8      // batch
#define NC 256    // channels
#define NN 1024   // spatial H*W
#define NICH 64   // inter channels

// ws layout (float offsets)
#define WS_AQ    0        // [256]
#define WS_AK    256      // [256]
#define WS_CQ    512
#define WS_CK    513
#define WS_GE    514
#define WS_MOM   520      // [32][4]: Seq,Sek,Sek2,Sekq partials per (b,qchunk)
#define WS_SX    1024     // [8][256]
#define WS_XE    3072     // [8][256]
#define WS_XK    5120     // [8][256]
#define WS_SX2P  7168     // [128]
#define WS_UUP   7296     // [128]
#define WS_T1P   7424     // [64]
#define WS_T2P   7488     // [64]
#define WS_VSU   7680     // [8][256]  u·1
#define WS_UE    9728     // [8][256]  u·eq
#define WS_VEU   11776    // [8][256]  u·ek
#define WS_CAQ   13824    // [8][256]  x·(u^T aq)
#define WS_CAK   15872    // [8][256]  x·(u^T ak)
#define WS_CUAK  17920    // [8][256]  u·(u^T ak)
#define WS_STAT  20480    // [8] stride 2560: eq,ek,Sv,Sve
#define STAT_STRIDE 2560
#define ST_EQ    0        // [1024]
#define ST_EK    1024     // [1024]
#define ST_SV    2048     // [256]
#define ST_SVE   2304     // [256]
#define WS_MAQ   40960    // [8][1024]  u^T aq
#define WS_MAK   49152    // [8][1024]  u^T ak
#define WS_EQP   57344    // [128][1024]
#define WS_EKP   188416   // [128][1024]
#define WS_MAQP  319488   // [128][1024]
#define WS_MAKP  450560   // [128][1024] ends 581632 floats

// k1: per (b,16-ch group): eq/ek partials and maq/mak partials over n, sx per channel.
__global__ void k1(const float* __restrict__ x, const float* __restrict__ u,
                   const float* __restrict__ Wq, const float* __restrict__ bq,
                   const float* __restrict__ Wk, const float* __restrict__ bk,
                   const float* __restrict__ Wc, float* __restrict__ ws) {
    const int bid = blockIdx.x;          // 128: b*16+g
    const int b = bid >> 4, g = bid & 15;
    const int t = threadIdx.x;           // 256
    const int c0 = g * 16;
    __shared__ float aql[16], akl[16];
    __shared__ float sxw[16][4];
    if (t < 16) {
        float a = 0.f, k = 0.f;
        for (int o = 0; o < NICH; ++o) {
            a += Wc[o] * Wq[o * NC + c0 + t];
            k += Wc[NICH + o] * Wk[o * NC + c0 + t];
        }
        aql[t] = a; akl[t] = k;
        ws[WS_AQ + c0 + t] = a;
        ws[WS_AK + c0 + t] = k;
    }
    if (t == 16) { float s = 0.f; for (int o = 0; o < 64; ++o) s += Wc[o] * bq[o]; ws[WS_CQ] = s; }
    if (t == 17) { float s = 0.f; for (int o = 0; o < 64; ++o) s += Wc[NICH + o] * bk[o]; ws[WS_CK] = s; }
    __syncthreads();
    const float* xb = x + ((size_t)b * NC + c0) * NN;
    const float* ub = u + ((size_t)b * NC + c0) * NN;
    float eqp[4] = {0.f, 0.f, 0.f, 0.f}, ekp[4] = {0.f, 0.f, 0.f, 0.f};
    float map[4] = {0.f, 0.f, 0.f, 0.f}, mkp[4] = {0.f, 0.f, 0.f, 0.f};
    const int wid = t >> 6, lane = t & 63;
    for (int c = 0; c < 16; ++c) {
        float a = aql[c], k = akl[c];
        float xs = 0.f;
#pragma unroll
        for (int jj = 0; jj < 4; ++jj) {
            float xv = xb[c * NN + t + 256 * jj];
            float uv = ub[c * NN + t + 256 * jj];
            eqp[jj] += a * xv; ekp[jj] += k * xv;
            map[jj] += a * uv; mkp[jj] += k * uv;
            xs += xv;
        }
        for (int off = 32; off > 0; off >>= 1) xs += __shfl_down(xs, off, 64);
        if (lane == 0) sxw[c][wid] = xs;
    }
    __syncthreads();
    if (t < 16) ws[WS_SX + b * NC + c0 + t] = sxw[t][0] + sxw[t][1] + sxw[t][2] + sxw[t][3];
    size_t pb = (size_t)bid * 1024;
#pragma unroll
    for (int jj = 0; jj < 4; ++jj) {
        ws[WS_EQP  + pb + t + 256 * jj] = eqp[jj];
        ws[WS_EKP  + pb + t + 256 * jj] = ekp[jj];
        ws[WS_MAQP + pb + t + 256 * jj] = map[jj];
        ws[WS_MAKP + pb + t + 256 * jj] = mkp[jj];
    }
}

// k2: finalize eq/ek + maq/mak, 4 moments (Seq, Sek, Sek2, Sekq)
__global__ void k2(float* __restrict__ ws) {
    const int bid = blockIdx.x;      // 32: b*4+qc
    const int b = bid >> 2, qc = bid & 3;
    const int t = threadIdx.x;       // 256
    const int n = qc * 256 + t;
    const float cq = ws[WS_CQ], ck = ws[WS_CK];
    float e = 0.f, k = 0.f, ma = 0.f, mk = 0.f;
    for (int g = 0; g < 16; ++g) {
        size_t pb = (size_t)(b * 16 + g) * 1024 + n;
        e  += ws[WS_EQP  + pb];
        k  += ws[WS_EKP  + pb];
        ma += ws[WS_MAQP + pb];
        mk += ws[WS_MAKP + pb];
    }
    e += cq; k += ck;
    float* st = ws + WS_STAT + b * STAT_STRIDE;
    st[ST_EQ + n] = e;
    st[ST_EK + n] = k;
    ws[WS_MAQ + b * NN + n] = ma;
    ws[WS_MAK + b * NN + n] = mk;
    float d[4] = {e, k, k * k, e * k};
    __shared__ float dred[4][4];
    const int wid = t >> 6, lane = t & 63;
    for (int off = 32; off > 0; off >>= 1)
        for (int m = 0; m < 4; ++m) d[m] += __shfl_down(d[m], off, 64);
    if (lane == 0) for (int m = 0; m < 4; ++m) dred[m][wid] = d[m];
    __syncthreads();
    if (t == 0)
        for (int m = 0; m < 4; ++m)
            ws[WS_MOM + bid * 4 + m] = dred[m][0] + dred[m][1] + dred[m][2] + dred[m][3];
}

// k3: fused row-dots over x and u
__global__ void k3(const float* __restrict__ x, const float* __restrict__ u,
                   float* __restrict__ ws) {
    const int bid = blockIdx.x;   // 128: b*16+g
    const int b = bid >> 4, g = bid & 15;
    const int t = threadIdx.x;    // 256
    const int c0 = g * 16;
    __shared__ float eql[NN], ekl[NN], maql[NN], makl[NN];
    __shared__ float wv8[16][8][4];
    __shared__ float accw[2][4];
    const float* st = ws + WS_STAT + b * STAT_STRIDE;
    for (int j = 0; j < 4; ++j) {
        int n = t + 256 * j;
        eql[n]  = st[ST_EQ + n];
        ekl[n]  = st[ST_EK + n];
        maql[n] = ws[WS_MAQ + b * NN + n];
        makl[n] = ws[WS_MAK + b * NN + n];
    }
    __syncthreads();
    const float* xb = x + ((size_t)b * NC + c0) * NN;
    const float* ub = u + ((size_t)b * NC + c0) * NN;
    float x2a = 0.f, uua = 0.f;
    const int wid = t >> 6, lane = t & 63;
    for (int c = 0; c < 16; ++c) {
        float d[8] = {0.f, 0.f, 0.f, 0.f, 0.f, 0.f, 0.f, 0.f};
        for (int j = 0; j < 4; ++j) {
            int n = t + 256 * j;
            float xv = xb[c * NN + n], uv = ub[c * NN + n];
            float e = eql[n], kk = ekl[n], ma = maql[n], mk = makl[n];
            d[0] += xv * e;   // xe
            d[1] += xv * kk;  // xk
            d[2] += uv;       // Vsu
            d[3] += uv * e;   // Ue
            d[4] += uv * kk;  // Veu
            d[5] += xv * ma;  // caq
            d[6] += xv * mk;  // cak
            d[7] += uv * mk;  // cuak
            x2a += xv * xv;
            uua += uv * uv;
        }
        for (int off = 32; off > 0; off >>= 1)
            for (int m = 0; m < 8; ++m) d[m] += __shfl_down(d[m], off, 64);
        if (lane == 0) for (int m = 0; m < 8; ++m) wv8[c][m][wid] = d[m];
    }
    for (int off = 32; off > 0; off >>= 1) {
        x2a += __shfl_down(x2a, off, 64);
        uua += __shfl_down(uua, off, 64);
    }
    if (lane == 0) { accw[0][wid] = x2a; accw[1][wid] = uua; }
    __syncthreads();
    if (t < 16) {
        int c = t;
        float v[8];
        for (int m = 0; m < 8; ++m)
            v[m] = wv8[c][m][0] + wv8[c][m][1] + wv8[c][m][2] + wv8[c][m][3];
        ws[WS_XE   + b * NC + c0 + c] = v[0];
        ws[WS_XK   + b * NC + c0 + c] = v[1];
        ws[WS_VSU  + b * NC + c0 + c] = v[2];
        ws[WS_UE   + b * NC + c0 + c] = v[3];
        ws[WS_VEU  + b * NC + c0 + c] = v[4];
        ws[WS_CAQ  + b * NC + c0 + c] = v[5];
        ws[WS_CAK  + b * NC + c0 + c] = v[6];
        ws[WS_CUAK + b * NC + c0 + c] = v[7];
    }
    if (t == 0) {
        ws[WS_SX2P + bid] = accw[0][0] + accw[0][1] + accw[0][2] + accw[0][3];
        ws[WS_UUP + bid]  = accw[1][0] + accw[1][1] + accw[1][2] + accw[1][3];
    }
}

// ksv: Sv/Sve matvec (coalesced float4) + per-block T1/T2 partials for d2
__global__ void ksv(const float* __restrict__ Wv, const float* __restrict__ bv,
                    float* __restrict__ ws) {
    const int bid = blockIdx.x;          // 64: b*8 + oc
    const int b = bid >> 3, oc = bid & 7;
    const int t = threadIdx.x;           // 256
    const int o_sub = t >> 3, ks = t & 7;
    const int o = oc * 32 + o_sub;
    __shared__ float sxl[NC], xel[NC];
    __shared__ float T1s[32], T2s[32];
    sxl[t] = ws[WS_SX + b * NC + t];
    xel[t] = ws[WS_XE + b * NC + t];
    __syncthreads();
    float Seq = 0.f, Sek = 0.f, Sek2 = 0.f;
    for (int q = 0; q < 4; ++q) {
        Seq  += ws[WS_MOM + (b * 4 + q) * 4 + 0];
        Sek  += ws[WS_MOM + (b * 4 + q) * 4 + 1];
        Sek2 += ws[WS_MOM + (b * 4 + q) * 4 + 2];
    }
    const float cq = ws[WS_CQ], ck = ws[WS_CK];
    float wsx = 0.f, wxe = 0.f;
    const float4* wrow = (const float4*)(Wv + (size_t)o * NC);
#pragma unroll
    for (int i = 0; i < 8; ++i) {
        float4 w4 = wrow[i * 8 + ks];
        int k = i * 32 + ks * 4;
        wsx += w4.x * sxl[k] + w4.y * sxl[k + 1] + w4.z * sxl[k + 2] + w4.w * sxl[k + 3];
        wxe += w4.x * xel[k] + w4.y * xel[k + 1] + w4.z * xel[k + 2] + w4.w * xel[k + 3];
    }
    for (int off = 4; off > 0; off >>= 1) {
        wsx += __shfl_down(wsx, off, 8);
        wxe += __shfl_down(wxe, off, 8);
    }
    if (ks == 0) {
        float bvc = bv[o];
        float Sv  = wsx + (float)NN * bvc;
        float SvL = wsx;
        float Sve = wxe + bvc * Seq;
        float* st = ws + WS_STAT + b * STAT_STRIDE;
        st[ST_SV + o] = Sv; st[ST_SVE + o] = Sve;
        float A = 2.f * Sve - bvc * Seq - cq * Sv;
        float sx = sxl[o];
        float xk = ws[WS_XK + b * NC + o];
        float xkL = xk - ck * sx;
        float T1c = A * sx + Sv * xkL + SvL * xk;
        float SP  = Sek - (float)NN * ck;
        float SP2 = Sek2 - 2.f * ck * Sek + (float)NN * ck * ck;
        float SPQ = Sek2 - ck * Sek;
        float T2c = (float)NN * A * A + Sv * Sv * SP2 + SvL * SvL * Sek2
                  + 2.f * A * Sv * SP + 2.f * A * SvL * Sek + 2.f * Sv * SvL * SPQ;
        T1s[o_sub] = T1c; T2s[o_sub] = T2c;
    }
    __syncthreads();
    if (t == 0) {
        float t1 = 0.f, t2 = 0.f;
        for (int i = 0; i < 32; ++i) { t1 += T1s[i]; t2 += T2s[i]; }
        ws[WS_T1P + bid] = t1;
        ws[WS_T2P + bid] = t2;
    }
}

// kiter: closed-form 5-term vjp/trace recursion.
// Wv staged ONCE into LDS as packed bf16x2 (128KB) via coalesced row-segment
// loads; the 5 sequential matvecs then run entirely from LDS (no global
// latency in the loop — rounds 4-6 showed the L2-strided inner loop is
// latency-serialized at ~130cy/load regardless of access shape).
// bf16 Wv touches ONLY the trace-correction dots (~0.2% rel on terms that are
// orders below the 4116 threshold); output-0's Sv/Sve/ge stay f32 via ksv.
__global__ void kiter(
        const float* __restrict__ Wv, const float* __restrict__ bv,
        const float* __restrict__ gamma, float* __restrict__ ws,
        float* __restrict__ out) {
    const int b = blockIdx.x;            // 8
    const int t = threadIdx.x;           // 1024
    const int o = t & 255, q = t >> 8;
    const int wid4 = o >> 6, lane = t & 63;
    __shared__ unsigned int Wlds[128 * 256];  // 128KB: pair i=c/2, [i][o]
    __shared__ float VV[2 * NC];         // interleaved Vs/Ve
    __shared__ float redPR[2 * 1024];
    __shared__ float dred[9][4];
    __shared__ float gred[3][2];
    __shared__ float sge;
    // ---- stage Wv -> LDS bf16x2 (issue loads first; independent & coalesced)
#pragma unroll 4
    for (int r = 0; r < 32; ++r) {
        int c = r * 8 + q * 2;
        float w0 = Wv[(size_t)c * NC + o];
        float w1 = Wv[(size_t)(c + 1) * NC + o];
        unsigned int b0 = __float_as_uint(w0);
        unsigned int b1 = __float_as_uint(w1);
        b0 = (b0 + 0x7FFFu + ((b0 >> 16) & 1u)) >> 16;      // RNE bf16
        b1 = (b1 + 0x7FFFu + ((b1 >> 16) & 1u)) & 0xFFFF0000u;
        Wlds[(r * 4 + q) * 256 + o] = b0 | b1;
    }
    // gamma_eff: dd/xx are LINEAR in the partials -> 3 global sums, wave-parallel
    {
        float a = 0.f, b1 = 0.f, c1 = 0.f;
        if (t < 128) a = ws[WS_SX2P + t];
        if (t < 64) { b1 = ws[WS_T1P + t]; c1 = ws[WS_T2P + t]; }
        for (int off = 32; off > 0; off >>= 1) {
            a  += __shfl_down(a,  off, 64);
            b1 += __shfl_down(b1, off, 64);
            c1 += __shfl_down(c1, off, 64);
        }
        if (t < 128 && lane == 0) { gred[0][t >> 6] = a; gred[1][t >> 6] = b1; gred[2][t >> 6] = c1; }
    }
    __syncthreads();
    if (t == 0) {
        float S1 = gred[0][0] + gred[0][1];
        float T1 = gred[1][0] + gred[1][1];
        float T2 = gred[2][0] + gred[2][1];
        float inv = gamma[0] * (1.f / (float)NN);
        float dd = S1 + 2.f * inv * T1 + inv * inv * T2;
        float lip = sqrtf(dd / S1);
        float ge = gamma[0] * ((lip > 0.9f) ? (0.9f / lip) : 1.f);
        sge = ge;
        if (b == 0) ws[WS_GE] = ge;
    }
    __syncthreads();
    const float s = sge * (1.f / (float)NN);
    // per-channel constants (t<256)
    float Svl_r = 0.f, sxl_r = 0.f, xkl_r = 0.f, caql_r = 0.f, cakl_r = 0.f,
          Uel_r = 0.f, Vsul_r = 0.f, bvl_r = 0.f, aql_r = 0.f, akl_r = 0.f,
          veu_r = 0.f, cuak_r = 0.f, vsreg = 0.f, vereg = 0.f;
    if (t < 256) {
        const float* st = ws + WS_STAT + b * STAT_STRIDE;
        Svl_r  = st[ST_SV + t];
        sxl_r  = ws[WS_SX   + b * NC + t];
        xkl_r  = ws[WS_XK   + b * NC + t];
        caql_r = ws[WS_CAQ  + b * NC + t];
        cakl_r = ws[WS_CAK  + b * NC + t];
        Uel_r  = ws[WS_UE   + b * NC + t];
        Vsul_r = ws[WS_VSU  + b * NC + t];
        veu_r  = ws[WS_VEU  + b * NC + t];
        cuak_r = ws[WS_CUAK + b * NC + t];
        aql_r  = ws[WS_AQ + t];
        akl_r  = ws[WS_AK + t];
        bvl_r  = bv[t];
        vsreg = Vsul_r; vereg = veu_r;
        VV[2 * t] = vsreg; VV[2 * t + 1] = vereg;
    }
    float Seq = 0.f, Sek = 0.f, Sekq = 0.f;
    for (int qq = 0; qq < 4; ++qq) {
        Seq  += ws[WS_MOM + (b * 4 + qq) * 4 + 0];
        Sek  += ws[WS_MOM + (b * 4 + qq) * 4 + 1];
        Sekq += ws[WS_MOM + (b * 4 + qq) * 4 + 3];
    }
    float uu = 0.f;
    for (int g = 0; g < 16; ++g) uu += ws[WS_UUP + b * 16 + g];
    __syncthreads();
    // prologue dots
    if (t < 256) {
        float d[8] = {Svl_r * cuak_r, aql_r * Vsul_r, akl_r * Vsul_r, akl_r * Uel_r,
                      Svl_r * Vsul_r, Svl_r * veu_r,  Svl_r * aql_r,  Svl_r * akl_r};
        for (int off = 32; off > 0; off >>= 1)
            for (int m = 0; m < 8; ++m) d[m] += __shfl_down(d[m], off, 64);
        if (lane == 0) for (int m = 0; m < 8; ++m) dred[m][wid4] = d[m];
    }
    __syncthreads();
    float g2a = 0.f, aqVsu = 0.f, akVsu = 0.f, akUe = 0.f, SvVsu = 0.f, SvVeu = 0.f,
          Svaq = 0.f, Svak = 0.f;
    if (t < 256) {
        g2a   = dred[0][0] + dred[0][1] + dred[0][2] + dred[0][3];
        aqVsu = dred[1][0] + dred[1][1] + dred[1][2] + dred[1][3];
        akVsu = dred[2][0] + dred[2][1] + dred[2][2] + dred[2][3];
        akUe  = dred[3][0] + dred[3][1] + dred[3][2] + dred[3][3];
        SvVsu = dred[4][0] + dred[4][1] + dred[4][2] + dred[4][3];
        SvVeu = dred[5][0] + dred[5][1] + dred[5][2] + dred[5][3];
        Svaq  = dred[6][0] + dred[6][1] + dred[6][2] + dred[6][3];
        Svak  = dred[7][0] + dred[7][1] + dred[7][2] + dred[7][3];
    }
    __syncthreads();
    const float lam = 1.f + s * Svak;
    float alpha = 1.f, beta = 0.f, gam = 0.f;
    float SxAcc = 0.f, XkAcc = 0.f, CakAcc = 0.f;
    float dot = uu, tr = 0.f;
    const float coef[5] = {1.f, -0.5f, 1.f / 3.f, -0.25f, 0.2f};
    for (int j = 0; j < 5; ++j) {
        // matvec: 1024 threads, Wv from LDS (bf16x2), VV float4 broadcast
        float pa = 0.f, ra = 0.f;
#pragma unroll
        for (int ii = 0; ii < 32; ++ii) {
            int i = q * 32 + ii;
            unsigned int w = Wlds[i * 256 + o];
            float4 vv = ((const float4*)VV)[i];
            float wlo = __uint_as_float(w << 16);
            float whi = __uint_as_float(w & 0xFFFF0000u);
            pa += wlo * vv.x + whi * vv.z;
            ra += wlo * vv.y + whi * vv.w;
        }
        redPR[2 * t] = pa; redPR[2 * t + 1] = ra;
        __syncthreads();
        float Pv = 0.f, Rv = 0.f;
        if (t < 256) {
            Pv = s * (redPR[2 * t] + redPR[2 * (t + 256)] + redPR[2 * (t + 512)] + redPR[2 * (t + 768)]);
            Rv = s * (redPR[2 * t + 1] + redPR[2 * (t + 256) + 1] + redPR[2 * (t + 512) + 1] + redPR[2 * (t + 768) + 1]);
            float d[9];
            d[0] = Svl_r * Pv;    // svP
            d[1] = Svl_r * Rv;    // svR
            d[2] = bvl_r * vsreg; // bvVs
            d[3] = sxl_r * Pv;    // sxP
            d[4] = xkl_r * Pv;    // xkP
            d[5] = caql_r * Pv;   // caqP
            d[6] = cakl_r * Pv;   // cakP
            d[7] = Uel_r * Pv;    // ueP
            d[8] = Vsul_r * Rv;   // vsuR
            for (int off = 32; off > 0; off >>= 1)
                for (int m = 0; m < 9; ++m) d[m] += __shfl_down(d[m], off, 64);
            if (lane == 0) for (int m = 0; m < 9; ++m) dred[m][wid4] = d[m];
        }
        __syncthreads();
        if (t < 256) {
            float sm[9];
            for (int m = 0; m < 9; ++m) sm[m] = dred[m][0] + dred[m][1] + dred[m][2] + dred[m][3];
            const float svP = sm[0], svR = sm[1], bvVs = sm[2], sxP = sm[3], xkP = sm[4],
                        caqP = sm[5], cakP = sm[6], ueP = sm[7], vsuR = sm[8];
            const float sB = s * bvVs;
            float St  = s * (alpha * SvVsu + beta * (float)NN + gam * Seq  + Svaq * SxAcc);
            float tek = s * (alpha * SvVeu + beta * Sek        + gam * Sekq + Svaq * XkAcc);
            float uta = s * (alpha * g2a   + beta * akVsu      + gam * akUe + Svaq * CakAcc);
            dot += ueP + caqP + sB * aqVsu + uta + vsuR;
            tr  += coef[j] * dot;
            float nVs = vsreg + Pv * Seq  + aql_r * (sxP + (float)NN * sB) + akl_r * St  + Rv * (float)NN;
            float nVe = vereg + Pv * Sekq + aql_r * (xkP + sB * Sek)       + akl_r * tek + Rv * Sek;
            vsreg = nVs; vereg = nVe;
            VV[2 * t] = nVs; VV[2 * t + 1] = nVe;
            SxAcc  = lam * SxAcc  + sxP;
            XkAcc  = lam * XkAcc  + xkP;
            CakAcc = lam * CakAcc + cakP;
            beta = lam * beta + Svaq * sB + svR;
            gam  = lam * gam + svP;
            alpha *= lam;
        }
        __syncthreads();
    }
    if (t == 0) out[2097152 + b] = tr;
}

// Output 0: 2x + (ge/N)(Sve[c] + ek[m]*Sv[c]); ge from ws (written by kiter)
__global__ void kout0(const float* __restrict__ x, const float* __restrict__ ws,
                      float* __restrict__ out) {
    int bid = blockIdx.x;            // 2048: b*256 + c
    int b = bid >> 8, c = bid & 255, t = threadIdx.x;  // 256
    float ge = ws[WS_GE] * (1.f / (float)NN);
    const float* st = ws + WS_STAT + b * STAT_STRIDE;
    float sv = st[ST_SV + c], sve = st[ST_SVE + c];
    float4 ek4 = ((const float4*)(st + ST_EK))[t];
    size_t i4 = (size_t)bid * 256 + t;
    float4 x4 = ((const float4*)x)[i4];
    float4 o;
    o.x = 2.f * x4.x + ge * (sve + ek4.x * sv);
    o.y = 2.f * x4.y + ge * (sve + ek4.y * sv);
    o.z = 2.f * x4.z + ge * (sve + ek4.z * sv);
    o.w = 2.f * x4.w + ge * (sve + ek4.w * sv);
    ((float4*)out)[i4] = o;
}

extern "C" void kernel_launch(void* const* d_in, const int* in_sizes, int n_in,
                              void* d_out, int out_size, void* d_ws, size_t ws_size,
                              hipStream_t stream) {
    const float* x     = (const float*)d_in[0];
    const float* Wq    = (const float*)d_in[1];
    const float* bq    = (const float*)d_in[2];
    const float* Wk    = (const float*)d_in[3];
    const float* bk    = (const float*)d_in[4];
    const float* Wc    = (const float*)d_in[5];
    const float* Wv    = (const float*)d_in[6];
    const float* bv    = (const float*)d_in[7];
    const float* gamma = (const float*)d_in[8];
    const float* u     = (const float*)d_in[9];
    float* out = (float*)d_out;
    float* ws  = (float*)d_ws;

    k1   <<<dim3(128),  dim3(256),  0, stream>>>(x, u, Wq, bq, Wk, bk, Wc, ws);
    k2   <<<dim3(32),   dim3(256),  0, stream>>>(ws);
    k3   <<<dim3(128),  dim3(256),  0, stream>>>(x, u, ws);
    ksv  <<<dim3(64),   dim3(256),  0, stream>>>(Wv, bv, ws);
    kiter<<<dim3(8),    dim3(1024), 0, stream>>>(Wv, bv, gamma, ws, out);
    kout0<<<dim3(2048), dim3(256),  0, stream>>>(x, ws, out);
}

// Round 8
// 55.154 us; speedup vs baseline: 2.6075x; 1.6162x over previous
//
#include <hip/hip_runtime.h>
#include <math.h>

// Problem constants
#define NB 8      // batch
#define NC 256    // channels
#define NN 1024   // spatial H*W
#define NICH 64   // inter channels

// ws layout (float offsets)
#define WS_AQ    0        // [256]
#define WS_AK    256      // [256]
#define WS_CQ    512
#define WS_CK    513
#define WS_GE    514
#define WS_MOM   520      // [32][4]: Seq,Sek,Sek2,Sekq partials per (b,qchunk)
#define WS_SX    1024     // [8][256]
#define WS_XE    3072     // [8][256]
#define WS_XK    5120     // [8][256]  (ends 7168)
#define WS_T1P   7424     // [64]
#define WS_T2P   7488     // [64]
#define WS_VSU   7680     // [8][256]  u·1
#define WS_UE    9728     // [8][256]  u·eq
#define WS_VEU   11776    // [8][256]  u·ek
#define WS_CAQ   13824    // [8][256]  x·(u^T aq)
#define WS_CAK   15872    // [8][256]  x·(u^T ak)
#define WS_CUAK  17920    // [8][256]  u·(u^T ak)
#define WS_STAT  20480    // [8] stride 2560: eq,ek,Sv,Sve
#define STAT_STRIDE 2560
#define ST_EQ    0        // [1024]
#define ST_EK    1024     // [1024]
#define ST_SV    2048     // [256]
#define ST_SVE   2304     // [256]
#define WS_MAQ   40960    // [8][1024]  u^T aq
#define WS_MAK   49152    // [8][1024]  u^T ak
#define WS_EQP   57344    // [256][1024]
#define WS_EKP   319488   // [256][1024]
#define WS_MAQP  581632   // [256][1024]
#define WS_MAKP  843776   // [256][1024] ends 1105920
#define WS_SX2P  1105920  // [256]
#define WS_UUP   1106176  // [256] ends 1106432 (~4.43 MB)

__device__ __forceinline__ float dot4(const float4& a, const float4& b) {
    return a.x * b.x + a.y * b.y + a.z * b.z + a.w * b.w;
}
__device__ __forceinline__ float sum4(const float4& a) {
    return a.x + a.y + a.z + a.w;
}

// k1: per (b, 8-ch group): eq/ek + maq/mak partials over n (float4), sx per channel.
__global__ void k1(const float* __restrict__ x, const float* __restrict__ u,
                   const float* __restrict__ Wq, const float* __restrict__ bq,
                   const float* __restrict__ Wk, const float* __restrict__ bk,
                   const float* __restrict__ Wc, float* __restrict__ ws) {
    const int bid = blockIdx.x;          // 256: b*32+g
    const int b = bid >> 5, g = bid & 31;
    const int t = threadIdx.x;           // 256
    const int c0 = g * 8;
    const int wid = t >> 6, lane = t & 63;
    __shared__ float aql[8], akl[8];
    __shared__ float sxw[8][4];
    // aq/ak: channel c = t>>5, partial index i = t&31 (2 o-terms each)
    {
        const int c = t >> 5, i = t & 31;
        float a = Wc[i] * Wq[i * NC + c0 + c] + Wc[i + 32] * Wq[(i + 32) * NC + c0 + c];
        float k = Wc[64 + i] * Wk[i * NC + c0 + c] + Wc[96 + i] * Wk[(i + 32) * NC + c0 + c];
        for (int off = 16; off > 0; off >>= 1) {
            a += __shfl_down(a, off, 32);
            k += __shfl_down(k, off, 32);
        }
        if (i == 0) {
            aql[c] = a; akl[c] = k;
            ws[WS_AQ + c0 + c] = a;
            ws[WS_AK + c0 + c] = k;
        }
    }
    if (t < 64) {   // cq/ck in wave 0
        float p = Wc[t] * bq[t], r = Wc[64 + t] * bk[t];
        for (int off = 32; off > 0; off >>= 1) {
            p += __shfl_down(p, off, 64);
            r += __shfl_down(r, off, 64);
        }
        if (t == 0) { ws[WS_CQ] = p; ws[WS_CK] = r; }
    }
    __syncthreads();
    const float4* xb4 = (const float4*)(x + ((size_t)b * NC + c0) * NN);
    const float4* ub4 = (const float4*)(u + ((size_t)b * NC + c0) * NN);
    float4 eqp = {0.f, 0.f, 0.f, 0.f}, ekp = {0.f, 0.f, 0.f, 0.f};
    float4 map = {0.f, 0.f, 0.f, 0.f}, mkp = {0.f, 0.f, 0.f, 0.f};
#pragma unroll
    for (int c = 0; c < 8; ++c) {
        float4 xv = xb4[c * 256 + t];
        float4 uv = ub4[c * 256 + t];
        float a = aql[c], k = akl[c];
        eqp.x += a * xv.x; eqp.y += a * xv.y; eqp.z += a * xv.z; eqp.w += a * xv.w;
        ekp.x += k * xv.x; ekp.y += k * xv.y; ekp.z += k * xv.z; ekp.w += k * xv.w;
        map.x += a * uv.x; map.y += a * uv.y; map.z += a * uv.z; map.w += a * uv.w;
        mkp.x += k * uv.x; mkp.y += k * uv.y; mkp.z += k * uv.z; mkp.w += k * uv.w;
        float xs = sum4(xv);
        for (int off = 32; off > 0; off >>= 1) xs += __shfl_down(xs, off, 64);
        if (lane == 0) sxw[c][wid] = xs;
    }
    __syncthreads();
    if (t < 8) ws[WS_SX + b * NC + c0 + t] = sxw[t][0] + sxw[t][1] + sxw[t][2] + sxw[t][3];
    size_t pb = (size_t)bid * 1024;
    ((float4*)(ws + WS_EQP + pb))[t]  = eqp;
    ((float4*)(ws + WS_EKP + pb))[t]  = ekp;
    ((float4*)(ws + WS_MAQP + pb))[t] = map;
    ((float4*)(ws + WS_MAKP + pb))[t] = mkp;
}

// k2: finalize eq/ek + maq/mak from 32 partials (float4), 4 moments
__global__ void k2(float* __restrict__ ws) {
    const int bid = blockIdx.x;      // 32: b*4+qc
    const int b = bid >> 2, qc = bid & 3;
    const int t = threadIdx.x;       // 256
    const int quarter = t >> 6, tn = t & 63;
    const int n4 = qc * 64 + tn;     // float4 group index within batch
    __shared__ float4 qb[4][4][64];  // [array][quarter][tn]
    float4 e4 = {0.f, 0.f, 0.f, 0.f}, k4 = {0.f, 0.f, 0.f, 0.f};
    float4 ma4 = {0.f, 0.f, 0.f, 0.f}, mk4 = {0.f, 0.f, 0.f, 0.f};
#pragma unroll
    for (int gg = 0; gg < 8; ++gg) {
        size_t pb = (size_t)(b * 32 + quarter * 8 + gg) * 1024;
        float4 v0 = ((const float4*)(ws + WS_EQP + pb))[n4];
        float4 v1 = ((const float4*)(ws + WS_EKP + pb))[n4];
        float4 v2 = ((const float4*)(ws + WS_MAQP + pb))[n4];
        float4 v3 = ((const float4*)(ws + WS_MAKP + pb))[n4];
        e4.x += v0.x; e4.y += v0.y; e4.z += v0.z; e4.w += v0.w;
        k4.x += v1.x; k4.y += v1.y; k4.z += v1.z; k4.w += v1.w;
        ma4.x += v2.x; ma4.y += v2.y; ma4.z += v2.z; ma4.w += v2.w;
        mk4.x += v3.x; mk4.y += v3.y; mk4.z += v3.z; mk4.w += v3.w;
    }
    qb[0][quarter][tn] = e4; qb[1][quarter][tn] = k4;
    qb[2][quarter][tn] = ma4; qb[3][quarter][tn] = mk4;
    __syncthreads();
    if (t < 64) {
        const float cq = ws[WS_CQ], ck = ws[WS_CK];
        float4 e = qb[0][0][t], kk = qb[1][0][t], ma = qb[2][0][t], mk = qb[3][0][t];
        for (int qq = 1; qq < 4; ++qq) {
            float4 a0 = qb[0][qq][t], a1 = qb[1][qq][t], a2 = qb[2][qq][t], a3 = qb[3][qq][t];
            e.x += a0.x; e.y += a0.y; e.z += a0.z; e.w += a0.w;
            kk.x += a1.x; kk.y += a1.y; kk.z += a1.z; kk.w += a1.w;
            ma.x += a2.x; ma.y += a2.y; ma.z += a2.z; ma.w += a2.w;
            mk.x += a3.x; mk.y += a3.y; mk.z += a3.z; mk.w += a3.w;
        }
        e.x += cq; e.y += cq; e.z += cq; e.w += cq;
        kk.x += ck; kk.y += ck; kk.z += ck; kk.w += ck;
        float* st = ws + WS_STAT + b * STAT_STRIDE;
        ((float4*)(st + ST_EQ))[n4] = e;
        ((float4*)(st + ST_EK))[n4] = kk;
        ((float4*)(ws + WS_MAQ + b * NN))[n4] = ma;
        ((float4*)(ws + WS_MAK + b * NN))[n4] = mk;
        float d0 = sum4(e);
        float d1 = sum4(kk);
        float d2 = dot4(kk, kk);
        float d3 = dot4(e, kk);
        for (int off = 32; off > 0; off >>= 1) {
            d0 += __shfl_down(d0, off, 64);
            d1 += __shfl_down(d1, off, 64);
            d2 += __shfl_down(d2, off, 64);
            d3 += __shfl_down(d3, off, 64);
        }
        if (t == 0) {
            ws[WS_MOM + bid * 4 + 0] = d0;
            ws[WS_MOM + bid * 4 + 1] = d1;
            ws[WS_MOM + bid * 4 + 2] = d2;
            ws[WS_MOM + bid * 4 + 3] = d3;
        }
    }
}

// k3: fused row-dots over x and u (float4; per-thread n-positions fixed ->
// eq/ek/maq/mak loaded once per thread from global, no LDS staging)
__global__ void k3(const float* __restrict__ x, const float* __restrict__ u,
                   float* __restrict__ ws) {
    const int bid = blockIdx.x;   // 256: b*32+g
    const int b = bid >> 5, g = bid & 31;
    const int t = threadIdx.x;    // 256
    const int c0 = g * 8;
    const int wid = t >> 6, lane = t & 63;
    __shared__ float wv8[8][8][4];
    __shared__ float accw[2][4];
    const float* st = ws + WS_STAT + b * STAT_STRIDE;
    float4 e4  = ((const float4*)(st + ST_EQ))[t];
    float4 k4v = ((const float4*)(st + ST_EK))[t];
    float4 ma4 = ((const float4*)(ws + WS_MAQ + b * NN))[t];
    float4 mk4 = ((const float4*)(ws + WS_MAK + b * NN))[t];
    const float4* xb4 = (const float4*)(x + ((size_t)b * NC + c0) * NN);
    const float4* ub4 = (const float4*)(u + ((size_t)b * NC + c0) * NN);
    float x2a = 0.f, uua = 0.f;
#pragma unroll
    for (int c = 0; c < 8; ++c) {
        float4 xv = xb4[c * 256 + t];
        float4 uv = ub4[c * 256 + t];
        float d[8];
        d[0] = dot4(xv, e4);   // xe
        d[1] = dot4(xv, k4v);  // xk
        d[2] = sum4(uv);       // Vsu
        d[3] = dot4(uv, e4);   // Ue
        d[4] = dot4(uv, k4v);  // Veu
        d[5] = dot4(xv, ma4);  // caq
        d[6] = dot4(xv, mk4);  // cak
        d[7] = dot4(uv, mk4);  // cuak
        x2a += dot4(xv, xv);
        uua += dot4(uv, uv);
        for (int off = 32; off > 0; off >>= 1)
            for (int m = 0; m < 8; ++m) d[m] += __shfl_down(d[m], off, 64);
        if (lane == 0) for (int m = 0; m < 8; ++m) wv8[c][m][wid] = d[m];
    }
    for (int off = 32; off > 0; off >>= 1) {
        x2a += __shfl_down(x2a, off, 64);
        uua += __shfl_down(uua, off, 64);
    }
    if (lane == 0) { accw[0][wid] = x2a; accw[1][wid] = uua; }
    __syncthreads();
    if (t < 8) {
        int c = t;
        float v[8];
        for (int m = 0; m < 8; ++m)
            v[m] = wv8[c][m][0] + wv8[c][m][1] + wv8[c][m][2] + wv8[c][m][3];
        ws[WS_XE   + b * NC + c0 + c] = v[0];
        ws[WS_XK   + b * NC + c0 + c] = v[1];
        ws[WS_VSU  + b * NC + c0 + c] = v[2];
        ws[WS_UE   + b * NC + c0 + c] = v[3];
        ws[WS_VEU  + b * NC + c0 + c] = v[4];
        ws[WS_CAQ  + b * NC + c0 + c] = v[5];
        ws[WS_CAK  + b * NC + c0 + c] = v[6];
        ws[WS_CUAK + b * NC + c0 + c] = v[7];
    }
    if (t == 0) {
        ws[WS_SX2P + bid] = accw[0][0] + accw[0][1] + accw[0][2] + accw[0][3];
        ws[WS_UUP + bid]  = accw[1][0] + accw[1][1] + accw[1][2] + accw[1][3];
    }
}

// ksv: Sv/Sve matvec (coalesced float4) + per-block T1/T2 partials for d2
__global__ void ksv(const float* __restrict__ Wv, const float* __restrict__ bv,
                    float* __restrict__ ws) {
    const int bid = blockIdx.x;          // 64: b*8 + oc
    const int b = bid >> 3, oc = bid & 7;
    const int t = threadIdx.x;           // 256
    const int o_sub = t >> 3, ks = t & 7;
    const int o = oc * 32 + o_sub;
    __shared__ float sxl[NC], xel[NC];
    __shared__ float T1s[32], T2s[32];
    sxl[t] = ws[WS_SX + b * NC + t];
    xel[t] = ws[WS_XE + b * NC + t];
    __syncthreads();
    float Seq = 0.f, Sek = 0.f, Sek2 = 0.f;
    for (int q = 0; q < 4; ++q) {
        Seq  += ws[WS_MOM + (b * 4 + q) * 4 + 0];
        Sek  += ws[WS_MOM + (b * 4 + q) * 4 + 1];
        Sek2 += ws[WS_MOM + (b * 4 + q) * 4 + 2];
    }
    const float cq = ws[WS_CQ], ck = ws[WS_CK];
    float wsx = 0.f, wxe = 0.f;
    const float4* wrow = (const float4*)(Wv + (size_t)o * NC);
#pragma unroll
    for (int i = 0; i < 8; ++i) {
        float4 w4 = wrow[i * 8 + ks];
        int k = i * 32 + ks * 4;
        wsx += w4.x * sxl[k] + w4.y * sxl[k + 1] + w4.z * sxl[k + 2] + w4.w * sxl[k + 3];
        wxe += w4.x * xel[k] + w4.y * xel[k + 1] + w4.z * xel[k + 2] + w4.w * xel[k + 3];
    }
    for (int off = 4; off > 0; off >>= 1) {
        wsx += __shfl_down(wsx, off, 8);
        wxe += __shfl_down(wxe, off, 8);
    }
    if (ks == 0) {
        float bvc = bv[o];
        float Sv  = wsx + (float)NN * bvc;
        float SvL = wsx;
        float Sve = wxe + bvc * Seq;
        float* st = ws + WS_STAT + b * STAT_STRIDE;
        st[ST_SV + o] = Sv; st[ST_SVE + o] = Sve;
        float A = 2.f * Sve - bvc * Seq - cq * Sv;
        float sx = sxl[o];
        float xk = ws[WS_XK + b * NC + o];
        float xkL = xk - ck * sx;
        float T1c = A * sx + Sv * xkL + SvL * xk;
        float SP  = Sek - (float)NN * ck;
        float SP2 = Sek2 - 2.f * ck * Sek + (float)NN * ck * ck;
        float SPQ = Sek2 - ck * Sek;
        float T2c = (float)NN * A * A + Sv * Sv * SP2 + SvL * SvL * Sek2
                  + 2.f * A * Sv * SP + 2.f * A * SvL * Sek + 2.f * Sv * SvL * SPQ;
        T1s[o_sub] = T1c; T2s[o_sub] = T2c;
    }
    __syncthreads();
    if (t == 0) {
        float t1 = 0.f, t2 = 0.f;
        for (int i = 0; i < 32; ++i) { t1 += T1s[i]; t2 += T2s[i]; }
        ws[WS_T1P + bid] = t1;
        ws[WS_T2P + bid] = t2;
    }
}

// kiter: closed-form 5-term vjp/trace recursion; Wv staged once into LDS bf16x2.
__global__ void kiter(
        const float* __restrict__ Wv, const float* __restrict__ bv,
        const float* __restrict__ gamma, float* __restrict__ ws,
        float* __restrict__ out) {
    const int b = blockIdx.x;            // 8
    const int t = threadIdx.x;           // 1024
    const int o = t & 255, q = t >> 8;
    const int wid4 = o >> 6, lane = t & 63;
    __shared__ unsigned int Wlds[128 * 256];  // 128KB: pair i=c/2, [i][o]
    __shared__ float VV[2 * NC];
    __shared__ float redPR[2 * 1024];
    __shared__ float dred[9][4];
    __shared__ float gred0[4];
    __shared__ float gredT[2];
    __shared__ float sge;
    // ---- stage Wv -> LDS bf16x2
#pragma unroll 4
    for (int r = 0; r < 32; ++r) {
        int c = r * 8 + q * 2;
        float w0 = Wv[(size_t)c * NC + o];
        float w1 = Wv[(size_t)(c + 1) * NC + o];
        unsigned int b0 = __float_as_uint(w0);
        unsigned int b1 = __float_as_uint(w1);
        b0 = (b0 + 0x7FFFu + ((b0 >> 16) & 1u)) >> 16;      // RNE bf16
        b1 = (b1 + 0x7FFFu + ((b1 >> 16) & 1u)) & 0xFFFF0000u;
        Wlds[(r * 4 + q) * 256 + o] = b0 | b1;
    }
    // gamma_eff from SX2P[256] / T1P[64] / T2P[64]
    {
        float a = 0.f, b1 = 0.f, c1 = 0.f;
        if (t < 256) a = ws[WS_SX2P + t];
        if (t < 64) { b1 = ws[WS_T1P + t]; c1 = ws[WS_T2P + t]; }
        for (int off = 32; off > 0; off >>= 1) {
            a  += __shfl_down(a,  off, 64);
            b1 += __shfl_down(b1, off, 64);
            c1 += __shfl_down(c1, off, 64);
        }
        if (t < 256 && lane == 0) gred0[t >> 6] = a;
        if (t == 0) { gredT[0] = b1; gredT[1] = c1; }
    }
    __syncthreads();
    if (t == 0) {
        float S1 = gred0[0] + gred0[1] + gred0[2] + gred0[3];
        float T1 = gredT[0];
        float T2 = gredT[1];
        float inv = gamma[0] * (1.f / (float)NN);
        float dd = S1 + 2.f * inv * T1 + inv * inv * T2;
        float lip = sqrtf(dd / S1);
        float ge = gamma[0] * ((lip > 0.9f) ? (0.9f / lip) : 1.f);
        sge = ge;
        if (b == 0) ws[WS_GE] = ge;
    }
    __syncthreads();
    const float s = sge * (1.f / (float)NN);
    // per-channel constants (t<256)
    float Svl_r = 0.f, sxl_r = 0.f, xkl_r = 0.f, caql_r = 0.f, cakl_r = 0.f,
          Uel_r = 0.f, Vsul_r = 0.f, bvl_r = 0.f, aql_r = 0.f, akl_r = 0.f,
          veu_r = 0.f, cuak_r = 0.f, vsreg = 0.f, vereg = 0.f;
    if (t < 256) {
        const float* st = ws + WS_STAT + b * STAT_STRIDE;
        Svl_r  = st[ST_SV + t];
        sxl_r  = ws[WS_SX   + b * NC + t];
        xkl_r  = ws[WS_XK   + b * NC + t];
        caql_r = ws[WS_CAQ  + b * NC + t];
        cakl_r = ws[WS_CAK  + b * NC + t];
        Uel_r  = ws[WS_UE   + b * NC + t];
        Vsul_r = ws[WS_VSU  + b * NC + t];
        veu_r  = ws[WS_VEU  + b * NC + t];
        cuak_r = ws[WS_CUAK + b * NC + t];
        aql_r  = ws[WS_AQ + t];
        akl_r  = ws[WS_AK + t];
        bvl_r  = bv[t];
        vsreg = Vsul_r; vereg = veu_r;
        VV[2 * t] = vsreg; VV[2 * t + 1] = vereg;
    }
    float Seq = 0.f, Sek = 0.f, Sekq = 0.f;
    for (int qq = 0; qq < 4; ++qq) {
        Seq  += ws[WS_MOM + (b * 4 + qq) * 4 + 0];
        Sek  += ws[WS_MOM + (b * 4 + qq) * 4 + 1];
        Sekq += ws[WS_MOM + (b * 4 + qq) * 4 + 3];
    }
    float uu = 0.f;
    for (int g = 0; g < 32; ++g) uu += ws[WS_UUP + b * 32 + g];
    __syncthreads();
    // prologue dots
    if (t < 256) {
        float d[8] = {Svl_r * cuak_r, aql_r * Vsul_r, akl_r * Vsul_r, akl_r * Uel_r,
                      Svl_r * Vsul_r, Svl_r * veu_r,  Svl_r * aql_r,  Svl_r * akl_r};
        for (int off = 32; off > 0; off >>= 1)
            for (int m = 0; m < 8; ++m) d[m] += __shfl_down(d[m], off, 64);
        if (lane == 0) for (int m = 0; m < 8; ++m) dred[m][wid4] = d[m];
    }
    __syncthreads();
    float g2a = 0.f, aqVsu = 0.f, akVsu = 0.f, akUe = 0.f, SvVsu = 0.f, SvVeu = 0.f,
          Svaq = 0.f, Svak = 0.f;
    if (t < 256) {
        g2a   = dred[0][0] + dred[0][1] + dred[0][2] + dred[0][3];
        aqVsu = dred[1][0] + dred[1][1] + dred[1][2] + dred[1][3];
        akVsu = dred[2][0] + dred[2][1] + dred[2][2] + dred[2][3];
        akUe  = dred[3][0] + dred[3][1] + dred[3][2] + dred[3][3];
        SvVsu = dred[4][0] + dred[4][1] + dred[4][2] + dred[4][3];
        SvVeu = dred[5][0] + dred[5][1] + dred[5][2] + dred[5][3];
        Svaq  = dred[6][0] + dred[6][1] + dred[6][2] + dred[6][3];
        Svak  = dred[7][0] + dred[7][1] + dred[7][2] + dred[7][3];
    }
    __syncthreads();
    const float lam = 1.f + s * Svak;
    float alpha = 1.f, beta = 0.f, gam = 0.f;
    float SxAcc = 0.f, XkAcc = 0.f, CakAcc = 0.f;
    float dot = uu, tr = 0.f;
    const float coef[5] = {1.f, -0.5f, 1.f / 3.f, -0.25f, 0.2f};
    for (int j = 0; j < 5; ++j) {
        // matvec: 1024 threads, Wv from LDS (bf16x2), VV float4 broadcast
        float pa = 0.f, ra = 0.f;
#pragma unroll
        for (int ii = 0; ii < 32; ++ii) {
            int i = q * 32 + ii;
            unsigned int w = Wlds[i * 256 + o];
            float4 vv = ((const float4*)VV)[i];
            float wlo = __uint_as_float(w << 16);
            float whi = __uint_as_float(w & 0xFFFF0000u);
            pa += wlo * vv.x + whi * vv.z;
            ra += wlo * vv.y + whi * vv.w;
        }
        redPR[2 * t] = pa; redPR[2 * t + 1] = ra;
        __syncthreads();
        float Pv = 0.f, Rv = 0.f;
        if (t < 256) {
            Pv = s * (redPR[2 * t] + redPR[2 * (t + 256)] + redPR[2 * (t + 512)] + redPR[2 * (t + 768)]);
            Rv = s * (redPR[2 * t + 1] + redPR[2 * (t + 256) + 1] + redPR[2 * (t + 512) + 1] + redPR[2 * (t + 768) + 1]);
            float d[9];
            d[0] = Svl_r * Pv;    // svP
            d[1] = Svl_r * Rv;    // svR
            d[2] = bvl_r * vsreg; // bvVs
            d[3] = sxl_r * Pv;    // sxP
            d[4] = xkl_r * Pv;    // xkP
            d[5] = caql_r * Pv;   // caqP
            d[6] = cakl_r * Pv;   // cakP
            d[7] = Uel_r * Pv;    // ueP
            d[8] = Vsul_r * Rv;   // vsuR
            for (int off = 32; off > 0; off >>= 1)
                for (int m = 0; m < 9; ++m) d[m] += __shfl_down(d[m], off, 64);
            if (lane == 0) for (int m = 0; m < 9; ++m) dred[m][wid4] = d[m];
        }
        __syncthreads();
        if (t < 256) {
            float sm[9];
            for (int m = 0; m < 9; ++m) sm[m] = dred[m][0] + dred[m][1] + dred[m][2] + dred[m][3];
            const float svP = sm[0], svR = sm[1], bvVs = sm[2], sxP = sm[3], xkP = sm[4],
                        caqP = sm[5], cakP = sm[6], ueP = sm[7], vsuR = sm[8];
            const float sB = s * bvVs;
            float St  = s * (alpha * SvVsu + beta * (float)NN + gam * Seq  + Svaq * SxAcc);
            float tek = s * (alpha * SvVeu + beta * Sek        + gam * Sekq + Svaq * XkAcc);
            float uta = s * (alpha * g2a   + beta * akVsu      + gam * akUe + Svaq * CakAcc);
            dot += ueP + caqP + sB * aqVsu + uta + vsuR;
            tr  += coef[j] * dot;
            float nVs = vsreg + Pv * Seq  + aql_r * (sxP + (float)NN * sB) + akl_r * St  + Rv * (float)NN;
            float nVe = vereg + Pv * Sekq + aql_r * (xkP + sB * Sek)       + akl_r * tek + Rv * Sek;
            vsreg = nVs; vereg = nVe;
            VV[2 * t] = nVs; VV[2 * t + 1] = nVe;
            SxAcc  = lam * SxAcc  + sxP;
            XkAcc  = lam * XkAcc  + xkP;
            CakAcc = lam * CakAcc + cakP;
            beta = lam * beta + Svaq * sB + svR;
            gam  = lam * gam + svP;
            alpha *= lam;
        }
        __syncthreads();
    }
    if (t == 0) out[2097152 + b] = tr;
}

// Output 0: 2x + (ge/N)(Sve[c] + ek[m]*Sv[c]); ge from ws (written by kiter)
__global__ void kout0(const float* __restrict__ x, const float* __restrict__ ws,
                      float* __restrict__ out) {
    int bid = blockIdx.x;            // 2048: b*256 + c
    int b = bid >> 8, c = bid & 255, t = threadIdx.x;  // 256
    float ge = ws[WS_GE] * (1.f / (float)NN);
    const float* st = ws + WS_STAT + b * STAT_STRIDE;
    float sv = st[ST_SV + c], sve = st[ST_SVE + c];
    float4 ek4 = ((const float4*)(st + ST_EK))[t];
    size_t i4 = (size_t)bid * 256 + t;
    float4 x4 = ((const float4*)x)[i4];
    float4 o;
    o.x = 2.f * x4.x + ge * (sve + ek4.x * sv);
    o.y = 2.f * x4.y + ge * (sve + ek4.y * sv);
    o.z = 2.f * x4.z + ge * (sve + ek4.z * sv);
    o.w = 2.f * x4.w + ge * (sve + ek4.w * sv);
    ((float4*)out)[i4] = o;
}

extern "C" void kernel_launch(void* const* d_in, const int* in_sizes, int n_in,
                              void* d_out, int out_size, void* d_ws, size_t ws_size,
                              hipStream_t stream) {
    const float* x     = (const float*)d_in[0];
    const float* Wq    = (const float*)d_in[1];
    const float* bq    = (const float*)d_in[2];
    const float* Wk    = (const float*)d_in[3];
    const float* bk    = (const float*)d_in[4];
    const float* Wc    = (const float*)d_in[5];
    const float* Wv    = (const float*)d_in[6];
    const float* bv    = (const float*)d_in[7];
    const float* gamma = (const float*)d_in[8];
    const float* u     = (const float*)d_in[9];
    float* out = (float*)d_out;
    float* ws  = (float*)d_ws;

    k1   <<<dim3(256),  dim3(256),  0, stream>>>(x, u, Wq, bq, Wk, bk, Wc, ws);
    k2   <<<dim3(32),   dim3(256),  0, stream>>>(ws);
    k3   <<<dim3(256),  dim3(256),  0, stream>>>(x, u, ws);
    ksv  <<<dim3(64),   dim3(256),  0, stream>>>(Wv, bv, ws);
    kiter<<<dim3(8),    dim3(1024), 0, stream>>>(Wv, bv, gamma, ws, out);
    kout0<<<dim3(2048), dim3(256),  0, stream>>>(x, ws, out);
}